// Round 2
// baseline (934.207 us; speedup 1.0000x reference)
//
#include <hip/hip_runtime.h>
#include <hip/hip_bf16.h>

// NNConv GNN, round 2:
//  P = h @ [K_0|...|K_15|Bmat] via split-bf16 MFMA (fp32-accurate: AhBh+AhBl+AlBh)
//  Proot = h @ root_w same way.
//  Edge phase: CSR-by-src (phase1: msg per edge, P row in regs) then
//  CSR-by-dst (phase2: sum msg + fused mean/root/bias/relu epilogue). No atomics
//  in the hot path; CSRs built once per call (counts -> scan -> fill).

#define NN 20000
#define NE 100000
#define WD 64
#define PCOLS 1088      // 16 K-blocks + bias block
#define DEPTH 6

typedef __attribute__((ext_vector_type(8))) short bf16x8;
typedef __attribute__((ext_vector_type(4))) float f32x4;

__device__ __forceinline__ unsigned short f2bf(float v) {
    union { float f; unsigned u; } x; x.f = v;
    unsigned r = x.u + 0x7fffu + ((x.u >> 16) & 1u);
    return (unsigned short)(r >> 16);
}
__device__ __forceinline__ float bf2f(unsigned short b) {
    union { unsigned u; float f; } x; x.u = ((unsigned)b) << 16;
    return x.f;
}

// ---------------- per-node in/out degree counts ----------------
__global__ __launch_bounds__(256) void count_kernel(const int* __restrict__ ei,
                                                    int* __restrict__ outc,
                                                    int* __restrict__ inc)
{
    int e = blockIdx.x * 256 + threadIdx.x;
    if (e >= NE) return;
    atomicAdd(&outc[ei[e]], 1);
    atomicAdd(&inc[ei[NE + e]], 1);
}

// ---------------- exclusive scan over [outc | inc] (40000 ints), 1 block ----
__global__ __launch_bounds__(256) void scan_kernel(const int* __restrict__ cnt,
                                                   int* __restrict__ rps,
                                                   int* __restrict__ rpd,
                                                   float* __restrict__ invd)
{
    __shared__ int sd[256];
    __shared__ int sbase;
    int t = threadIdx.x;
    if (t == 0) sbase = 0;
    __syncthreads();
    for (int c0 = 0; c0 < 2 * NN; c0 += 256) {
        int idx = c0 + t;
        int v = (idx < 2 * NN) ? cnt[idx] : 0;
        sd[t] = v;
        __syncthreads();
        for (int off = 1; off < 256; off <<= 1) {
            int x = (t >= off) ? sd[t - off] : 0;
            __syncthreads();
            sd[t] += x;
            __syncthreads();
        }
        int excl = sbase + sd[t] - v;   // exclusive prefix
        int tot  = sd[255];
        __syncthreads();
        if (idx < NN) {
            rps[idx] = excl;
        } else if (idx < 2 * NN) {
            rpd[idx - NN] = excl - NE;  // second half offset by total out = NE
            invd[idx - NN] = 1.0f / fmaxf((float)v, 1.0f);
        }
        if (t == 0) sbase += tot;
        __syncthreads();
    }
    if (t == 0) { rps[NN] = NE; rpd[NN] = NE; }
}

// ---------------- ek MLP + CSR fill (both src and dst lists) ----------------
__global__ __launch_bounds__(256) void ekfill_kernel(
    const int* __restrict__ ei, const float* __restrict__ ea,
    const float* __restrict__ k1w, const float* __restrict__ k1b,
    const int* __restrict__ rps, const int* __restrict__ rpd,
    int* __restrict__ fs, int* __restrict__ fd,
    float* __restrict__ eks, int* __restrict__ slotidx)
{
    int e = blockIdx.x * 256 + threadIdx.x;
    if (e >= NE) return;
    int s = ei[e], d = ei[NE + e];
    float a[6];
#pragma unroll
    for (int i = 0; i < 6; ++i) a[i] = ea[e * 6 + i];
    int slot_s = rps[s] + atomicAdd(&fs[s], 1);
    int slot_d = rpd[d] + atomicAdd(&fd[d], 1);
    slotidx[slot_d] = slot_s;
#pragma unroll
    for (int j = 0; j < 16; ++j) {
        float v = k1b[j];
#pragma unroll
        for (int i = 0; i < 6; ++i) v = fmaf(a[i], k1w[i * 16 + j], v);
        eks[(size_t)slot_s * 16 + j] = fmaxf(v, 0.f);
    }
}

// ---------------- GwT hi/lo bf16, [1152 rows n][64 cols k] -----------------
__global__ __launch_bounds__(256) void gwt_kernel(
    const float* __restrict__ k2w, const float* __restrict__ k2b,
    const float* __restrict__ rootw,
    unsigned short* __restrict__ Gh, unsigned short* __restrict__ Gl)
{
    int idx = blockIdx.x * 256 + threadIdx.x;   // 1152*64
    if (idx >= 1152 * 64) return;
    int n = idx >> 6, k = idx & 63;
    int b = n >> 6, o = n & 63;
    float g;
    if (b < 16)       g = k2w[b * 4096 + k * 64 + o];
    else if (b == 16) g = k2b[k * 64 + o];
    else              g = rootw[k * 64 + o];
    unsigned short hi = f2bf(g);
    Gh[idx] = hi;
    Gl[idx] = f2bf(g - bf2f(hi));
}

// ---------------- h0 = x*fc1_w + fc1_b -> hi/lo bf16 ----------------
__global__ __launch_bounds__(256) void h0_kernel(
    const float* __restrict__ x, const float* __restrict__ w,
    const float* __restrict__ b,
    unsigned short* __restrict__ hhi, unsigned short* __restrict__ hlo)
{
    int idx = blockIdx.x * 256 + threadIdx.x;
    if (idx >= NN * WD) return;
    int n = idx >> 6, o = idx & 63;
    float v = fmaf(x[n], w[o], b[o]);
    unsigned short hi = f2bf(v);
    hhi[idx] = hi;
    hlo[idx] = f2bf(v - bf2f(hi));
}

// ---------------- split-bf16 MFMA GEMM: out = (hhi+hlo) @ GwT^T -------------
// wave tile: 16m x 64n (4 n-tiles of 16), K=64 (2 k-halves), 6 MFMAs/tile.
__global__ __launch_bounds__(256) void gemm_kernel(
    const unsigned short* __restrict__ hhi, const unsigned short* __restrict__ hlo,
    const unsigned short* __restrict__ Gh, const unsigned short* __restrict__ Gl,
    float* __restrict__ out, int m_lo, int m_tiles, int n_strips, int b_row0,
    int ostride)
{
    int wid = blockIdx.x * 4 + (threadIdx.x >> 6);
    if (wid >= m_tiles * n_strips) return;
    int mt = wid % m_tiles, st = wid / m_tiles;
    int l = threadIdx.x & 63;
    int quad = l >> 4, lr = l & 15;
    int arow = m_lo + mt * 16 + lr;
    const bf16x8* pah = (const bf16x8*)(hhi + (size_t)arow * 64 + quad * 8);
    const bf16x8* pal = (const bf16x8*)(hlo + (size_t)arow * 64 + quad * 8);
    bf16x8 ah0 = pah[0], ah1 = pah[4];   // k 0..31, 32..63
    bf16x8 al0 = pal[0], al1 = pal[4];
    f32x4 acc[4];
#pragma unroll
    for (int t = 0; t < 4; ++t) acc[t] = (f32x4){0.f, 0.f, 0.f, 0.f};
#pragma unroll
    for (int t = 0; t < 4; ++t) {
        int brow = b_row0 + st * 64 + t * 16 + lr;
        const bf16x8* pbh = (const bf16x8*)(Gh + (size_t)brow * 64 + quad * 8);
        const bf16x8* pbl = (const bf16x8*)(Gl + (size_t)brow * 64 + quad * 8);
        bf16x8 bh0 = pbh[0], bh1 = pbh[4];
        bf16x8 bl0 = pbl[0], bl1 = pbl[4];
        f32x4 a = acc[t];
        a = __builtin_amdgcn_mfma_f32_16x16x32_bf16(ah0, bh0, a, 0, 0, 0);
        a = __builtin_amdgcn_mfma_f32_16x16x32_bf16(ah0, bl0, a, 0, 0, 0);
        a = __builtin_amdgcn_mfma_f32_16x16x32_bf16(al0, bh0, a, 0, 0, 0);
        a = __builtin_amdgcn_mfma_f32_16x16x32_bf16(ah1, bh1, a, 0, 0, 0);
        a = __builtin_amdgcn_mfma_f32_16x16x32_bf16(ah1, bl1, a, 0, 0, 0);
        a = __builtin_amdgcn_mfma_f32_16x16x32_bf16(al1, bh1, a, 0, 0, 0);
        acc[t] = a;
    }
    // C/D layout: col = lane&15, row = (lane>>4)*4 + reg   [m89-verified]
#pragma unroll
    for (int t = 0; t < 4; ++t) {
        int col = st * 64 + t * 16 + lr;
        int rbase = mt * 16 + quad * 4;
#pragma unroll
        for (int r = 0; r < 4; ++r)
            out[(size_t)(rbase + r) * ostride + col] = acc[t][r];
    }
}

// ---------------- phase 1: per-src msg, P row cached in registers -----------
__global__ __launch_bounds__(256) void msg_kernel(
    const float* __restrict__ P, const float* __restrict__ eks,
    const int* __restrict__ rps, float* __restrict__ msg, int m_lo, int m_cnt)
{
    int wv = blockIdx.x * 4 + (threadIdx.x >> 6);
    if (wv >= m_cnt) return;
    int i = m_lo + wv;
    int r0 = rps[i], r1 = rps[i + 1];
    if (r0 == r1) return;
    int l = threadIdx.x & 63;
    const float* Pr = P + (size_t)wv * PCOLS;
    float p[17];
#pragma unroll
    for (int k = 0; k < 17; ++k) p[k] = Pr[k * 64 + l];   // p[16] = bias block
    for (int s = r0; s < r1; ++s) {
        float ekv = eks[(size_t)s * 16 + (l & 15)];
        float m = p[16];
#pragma unroll
        for (int k = 0; k < 16; ++k) m = fmaf(__shfl(ekv, k, 64), p[k], m);
        msg[(size_t)s * 64 + l] = m;
    }
}

// ---------------- phase 2: per-dst sum + fused epilogue ----------------
__global__ __launch_bounds__(256) void agg_kernel(
    const float* __restrict__ msg, const int* __restrict__ slotidx,
    const int* __restrict__ rpd, const float* __restrict__ invd,
    const float* __restrict__ Proot, const float* __restrict__ convb,
    float* __restrict__ h, unsigned short* __restrict__ hhi,
    unsigned short* __restrict__ hlo)
{
    int i = blockIdx.x * 4 + (threadIdx.x >> 6);
    if (i >= NN) return;
    int l = threadIdx.x & 63;
    int r0 = rpd[i], r1 = rpd[i + 1];
    float acc = 0.f;
    for (int s = r0; s < r1; ++s) {
        int ss = slotidx[s];
        acc += msg[(size_t)ss * 64 + l];
    }
    float v = fmaf(acc, invd[i], Proot[(size_t)i * 64 + l] + convb[l]);
    v = fmaxf(v, 0.f);
    int idx = i * 64 + l;
    h[idx] = v;
    unsigned short hi = f2bf(v);
    hhi[idx] = hi;
    hlo[idx] = f2bf(v - bf2f(hi));
}

// ---------------- out = h @ fc2_w + fc2_b ----------------
__global__ __launch_bounds__(256) void out_kernel(
    const float* __restrict__ h, const float* __restrict__ fc2_w,
    const float* __restrict__ fc2_b, float* __restrict__ out)
{
    int wave = blockIdx.x * 4 + (threadIdx.x >> 6);
    int lane = threadIdx.x & 63;
    float v = h[(size_t)wave * 64 + lane] * fc2_w[lane];
#pragma unroll
    for (int off = 32; off > 0; off >>= 1) v += __shfl_down(v, off);
    if (lane == 0) out[wave] = v + fc2_b[0];
}

extern "C" void kernel_launch(void* const* d_in, const int* in_sizes, int n_in,
                              void* d_out, int out_size, void* d_ws, size_t ws_size,
                              hipStream_t stream)
{
    const float* x         = (const float*)d_in[0];
    const int*   ei        = (const int*)  d_in[1];
    const float* edge_attr = (const float*)d_in[2];
    const float* fc1_w     = (const float*)d_in[3];
    const float* fc1_b     = (const float*)d_in[4];
    const float* k1_w      = (const float*)d_in[5];
    const float* k1_b      = (const float*)d_in[6];
    const float* k2_w      = (const float*)d_in[7];
    const float* k2_b      = (const float*)d_in[8];
    const float* root_w    = (const float*)d_in[9];
    const float* conv_b    = (const float*)d_in[10];
    const float* fc2_w     = (const float*)d_in[11];
    const float* fc2_b     = (const float*)d_in[12];
    float* out = (float*)d_out;

    // workspace layout, f32 units (all segment sizes multiples of 4 -> 16B align)
    float* ws = (float*)d_ws;
    size_t off = 0;
    int* cnt   = (int*)(ws + off); off += 4 * NN;       // outc|inc|fs|fd
    int* outc  = cnt;
    int* inc   = cnt + NN;
    int* fs    = cnt + 2 * NN;
    int* fd    = cnt + 3 * NN;
    int* rps   = (int*)(ws + off); off += 20004;
    int* rpd   = (int*)(ws + off); off += 20004;
    int* slotidx = (int*)(ws + off); off += NE;
    float* invd  = ws + off; off += NN;
    float* eks   = ws + off; off += (size_t)NE * 16;
    unsigned short* Gh  = (unsigned short*)(ws + off); off += 36864;
    unsigned short* Gl  = (unsigned short*)(ws + off); off += 36864;
    unsigned short* hhi = (unsigned short*)(ws + off); off += (size_t)NN * 32;
    unsigned short* hlo = (unsigned short*)(ws + off); off += (size_t)NN * 32;
    float* h     = ws + off; off += (size_t)NN * WD;
    float* msg   = ws + off; off += (size_t)NE * WD;
    float* Proot = ws + off; off += (size_t)NN * WD;
    float* P     = ws + off;
    // full-P layout needs ~135.7 MB; halved ~92.1 MB.
    int halves = (ws_size >= (size_t)137000000) ? 1 : 2;
    int mchunk = NN / halves;

    hipMemsetAsync(cnt, 0, 4 * NN * sizeof(int), stream);
    count_kernel<<<(NE + 255) / 256, 256, 0, stream>>>(ei, outc, inc);
    scan_kernel<<<1, 256, 0, stream>>>(cnt, rps, rpd, invd);
    ekfill_kernel<<<(NE + 255) / 256, 256, 0, stream>>>(ei, edge_attr, k1_w, k1_b,
                                                        rps, rpd, fs, fd, eks, slotidx);
    gwt_kernel<<<(1152 * 64 + 255) / 256, 256, 0, stream>>>(k2_w, k2_b, root_w, Gh, Gl);
    h0_kernel<<<(NN * WD + 255) / 256, 256, 0, stream>>>(x, fc1_w, fc1_b, hhi, hlo);

    for (int layer = 0; layer < DEPTH; ++layer) {
        // Proot = h @ root_w  (full M, 1 strip, GwT rows 1088..1151)
        gemm_kernel<<<(1250 + 3) / 4, 256, 0, stream>>>(hhi, hlo, Gh, Gl, Proot,
                                                        0, 1250, 1, 1088, 64);
        for (int c = 0; c < halves; ++c) {
            int mlo = c * mchunk;
            int mtiles = mchunk / 16;
            int wv = mtiles * 17;
            gemm_kernel<<<(wv + 3) / 4, 256, 0, stream>>>(hhi, hlo, Gh, Gl, P,
                                                          mlo, mtiles, 17, 0, PCOLS);
            msg_kernel<<<(mchunk + 3) / 4, 256, 0, stream>>>(P, eks, rps, msg,
                                                             mlo, mchunk);
        }
        agg_kernel<<<(NN + 3) / 4, 256, 0, stream>>>(msg, slotidx, rpd, invd,
                                                     Proot, conv_b, h, hhi, hlo);
    }

    out_kernel<<<NN / 4, 256, 0, stream>>>(h, fc2_w, fc2_b, out);
}

// Round 3
// 733.721 us; speedup vs baseline: 1.2732x; 1.2732x over previous
//
#include <hip/hip_runtime.h>
#include <hip/hip_bf16.h>

// NNConv GNN, round 3:
//  P = h @ [K_0|...|K_15|Bmat] and Proot = h @ root_w fused in ONE split-bf16
//  MFMA GEMM (18 n-strips; strip 17 writes Proot at global rows).
//  Edge phase: CSR-by-src msg pass (P row in regs) then CSR-by-dst agg pass
//  with fused mean/root/bias/relu epilogue.
//  CSR built per call: count -> hierarchical 3-kernel scan -> fill.

#define NN 20000
#define NE 100000
#define WD 64
#define PCOLS 1088      // 16 K-blocks + bias block (root handled separately)
#define DEPTH 6

typedef __attribute__((ext_vector_type(8))) short bf16x8;
typedef __attribute__((ext_vector_type(4))) float f32x4;

__device__ __forceinline__ unsigned short f2bf(float v) {
    union { float f; unsigned u; } x; x.f = v;
    unsigned r = x.u + 0x7fffu + ((x.u >> 16) & 1u);
    return (unsigned short)(r >> 16);
}
__device__ __forceinline__ float bf2f(unsigned short b) {
    union { unsigned u; float f; } x; x.u = ((unsigned)b) << 16;
    return x.f;
}

// ---------------- per-node in/out degree counts ----------------
__global__ __launch_bounds__(256) void count_kernel(const int* __restrict__ ei,
                                                    int* __restrict__ outc,
                                                    int* __restrict__ inc)
{
    int e = blockIdx.x * 256 + threadIdx.x;
    if (e >= NE) return;
    atomicAdd(&outc[ei[e]], 1);
    atomicAdd(&inc[ei[NE + e]], 1);
}

// ---------------- hierarchical scan over [outc | inc] (40000 ints) ----------
// A: 40 blocks x 1024 elems -> per-block totals
__global__ __launch_bounds__(256) void scanA_kernel(const int* __restrict__ cnt,
                                                    int* __restrict__ partials)
{
    int b = blockIdx.x, t = threadIdx.x, lane = t & 63, w = t >> 6;
    int base = b * 1024 + t * 4;
    int s = 0;
#pragma unroll
    for (int i = 0; i < 4; ++i) {
        int idx = base + i;
        if (idx < 2 * NN) s += cnt[idx];
    }
#pragma unroll
    for (int off = 32; off > 0; off >>= 1) s += __shfl_down(s, off, 64);
    __shared__ int wsum[4];
    if (lane == 0) wsum[w] = s;
    __syncthreads();
    if (t == 0) partials[b] = wsum[0] + wsum[1] + wsum[2] + wsum[3];
}

// B: one wave exclusive-scans the 40 partials
__global__ __launch_bounds__(64) void scanB_kernel(const int* __restrict__ partials,
                                                   int* __restrict__ bases)
{
    int l = threadIdx.x;
    int p = (l < 40) ? partials[l] : 0;
    int v = p;
#pragma unroll
    for (int off = 1; off < 64; off <<= 1) {
        int u = __shfl_up(v, off, 64);
        if (l >= off) v += u;
    }
    if (l < 40) bases[l] = v - p;   // exclusive
}

// C: block-local scan + base add; writes rps/rpd/invd
__global__ __launch_bounds__(256) void scanC_kernel(const int* __restrict__ cnt,
                                                    const int* __restrict__ bases,
                                                    int* __restrict__ rps,
                                                    int* __restrict__ rpd,
                                                    float* __restrict__ invd)
{
    int b = blockIdx.x, t = threadIdx.x, lane = t & 63, w = t >> 6;
    int base = b * 1024 + t * 4;
    int v[4], s = 0;
#pragma unroll
    for (int i = 0; i < 4; ++i) {
        int idx = base + i;
        v[i] = (idx < 2 * NN) ? cnt[idx] : 0;
        s += v[i];
    }
    int tsum = s, sc = s;
#pragma unroll
    for (int off = 1; off < 64; off <<= 1) {
        int u = __shfl_up(sc, off, 64);
        if (lane >= off) sc += u;
    }
    __shared__ int wtot[4];
    if (lane == 63) wtot[w] = sc;
    __syncthreads();
    int wbase = 0;
    for (int j = 0; j < w; ++j) wbase += wtot[j];
    int run = bases[b] + wbase + sc - tsum;   // exclusive prefix at thread start
#pragma unroll
    for (int i = 0; i < 4; ++i) {
        int idx = base + i;
        int e = run; run += v[i];
        if (idx < NN) {
            rps[idx] = e;
        } else if (idx < 2 * NN) {
            rpd[idx - NN] = e - NE;           // first-half total == NE
            invd[idx - NN] = 1.0f / fmaxf((float)v[i], 1.0f);
        }
    }
    if (b == 0 && t == 0) { rps[NN] = NE; rpd[NN] = NE; }
}

// ---------------- ek MLP + CSR fill (both src and dst lists) ----------------
__global__ __launch_bounds__(256) void ekfill_kernel(
    const int* __restrict__ ei, const float* __restrict__ ea,
    const float* __restrict__ k1w, const float* __restrict__ k1b,
    const int* __restrict__ rps, const int* __restrict__ rpd,
    int* __restrict__ fs, int* __restrict__ fd,
    float* __restrict__ eks, int* __restrict__ slotidx)
{
    int e = blockIdx.x * 256 + threadIdx.x;
    if (e >= NE) return;
    int s = ei[e], d = ei[NE + e];
    float a[6];
#pragma unroll
    for (int i = 0; i < 6; ++i) a[i] = ea[e * 6 + i];
    int slot_s = rps[s] + atomicAdd(&fs[s], 1);
    int slot_d = rpd[d] + atomicAdd(&fd[d], 1);
    slotidx[slot_d] = slot_s;
#pragma unroll
    for (int j = 0; j < 16; ++j) {
        float v = k1b[j];
#pragma unroll
        for (int i = 0; i < 6; ++i) v = fmaf(a[i], k1w[i * 16 + j], v);
        eks[(size_t)slot_s * 16 + j] = fmaxf(v, 0.f);
    }
}

// ---------------- GwT hi/lo bf16, [1152 rows n][64 cols k] -----------------
__global__ __launch_bounds__(256) void gwt_kernel(
    const float* __restrict__ k2w, const float* __restrict__ k2b,
    const float* __restrict__ rootw,
    unsigned short* __restrict__ Gh, unsigned short* __restrict__ Gl)
{
    int idx = blockIdx.x * 256 + threadIdx.x;   // 1152*64
    if (idx >= 1152 * 64) return;
    int n = idx >> 6, k = idx & 63;
    int b = n >> 6, o = n & 63;
    float g;
    if (b < 16)       g = k2w[b * 4096 + k * 64 + o];
    else if (b == 16) g = k2b[k * 64 + o];
    else              g = rootw[k * 64 + o];
    unsigned short hi = f2bf(g);
    Gh[idx] = hi;
    Gl[idx] = f2bf(g - bf2f(hi));
}

// ---------------- h0 = x*fc1_w + fc1_b -> hi/lo bf16 ----------------
__global__ __launch_bounds__(256) void h0_kernel(
    const float* __restrict__ x, const float* __restrict__ w,
    const float* __restrict__ b,
    unsigned short* __restrict__ hhi, unsigned short* __restrict__ hlo)
{
    int idx = blockIdx.x * 256 + threadIdx.x;
    if (idx >= NN * WD) return;
    int n = idx >> 6, o = idx & 63;
    float v = fmaf(x[n], w[o], b[o]);
    unsigned short hi = f2bf(v);
    hhi[idx] = hi;
    hlo[idx] = f2bf(v - bf2f(hi));
}

// ---------------- split-bf16 MFMA GEMM, 18 strips (17 -> Proot) -------------
// wave tile: 16m x 64n (4 n-tiles of 16), K=64 (2 k-halves), 6 MFMAs/tile.
__global__ __launch_bounds__(256) void gemm_kernel(
    const unsigned short* __restrict__ hhi, const unsigned short* __restrict__ hlo,
    const unsigned short* __restrict__ Gh, const unsigned short* __restrict__ Gl,
    float* __restrict__ P, float* __restrict__ Proot, int m_lo, int m_tiles)
{
    int wid = blockIdx.x * 4 + (threadIdx.x >> 6);
    if (wid >= m_tiles * 18) return;
    int mt = wid % m_tiles, st = wid / m_tiles;
    int l = threadIdx.x & 63;
    int quad = l >> 4, lr = l & 15;
    int arow = m_lo + mt * 16 + lr;
    const bf16x8* pah = (const bf16x8*)(hhi + (size_t)arow * 64 + quad * 8);
    const bf16x8* pal = (const bf16x8*)(hlo + (size_t)arow * 64 + quad * 8);
    bf16x8 ah0 = pah[0], ah1 = pah[4];   // k 0..31, 32..63
    bf16x8 al0 = pal[0], al1 = pal[4];
    f32x4 acc[4];
#pragma unroll
    for (int t = 0; t < 4; ++t) acc[t] = (f32x4){0.f, 0.f, 0.f, 0.f};
#pragma unroll
    for (int t = 0; t < 4; ++t) {
        int brow = st * 64 + t * 16 + lr;
        const bf16x8* pbh = (const bf16x8*)(Gh + (size_t)brow * 64 + quad * 8);
        const bf16x8* pbl = (const bf16x8*)(Gl + (size_t)brow * 64 + quad * 8);
        bf16x8 bh0 = pbh[0], bh1 = pbh[4];
        bf16x8 bl0 = pbl[0], bl1 = pbl[4];
        f32x4 a = acc[t];
        a = __builtin_amdgcn_mfma_f32_16x16x32_bf16(ah0, bh0, a, 0, 0, 0);
        a = __builtin_amdgcn_mfma_f32_16x16x32_bf16(ah0, bl0, a, 0, 0, 0);
        a = __builtin_amdgcn_mfma_f32_16x16x32_bf16(al0, bh0, a, 0, 0, 0);
        a = __builtin_amdgcn_mfma_f32_16x16x32_bf16(ah1, bh1, a, 0, 0, 0);
        a = __builtin_amdgcn_mfma_f32_16x16x32_bf16(ah1, bl1, a, 0, 0, 0);
        a = __builtin_amdgcn_mfma_f32_16x16x32_bf16(al1, bh1, a, 0, 0, 0);
        acc[t] = a;
    }
    // C/D layout: col = lane&15, row = (lane>>4)*4 + reg   [m89-verified]
    int rbase = mt * 16 + quad * 4;
    if (st < 17) {
#pragma unroll
        for (int t = 0; t < 4; ++t) {
            int col = st * 64 + t * 16 + lr;
#pragma unroll
            for (int r = 0; r < 4; ++r)
                P[(size_t)(rbase + r) * PCOLS + col] = acc[t][r];
        }
    } else {
#pragma unroll
        for (int t = 0; t < 4; ++t) {
            int col = t * 16 + lr;
#pragma unroll
            for (int r = 0; r < 4; ++r)
                Proot[(size_t)(m_lo + rbase + r) * 64 + col] = acc[t][r];
        }
    }
}

// ---------------- phase 1: per-src msg, P row cached in registers -----------
__global__ __launch_bounds__(256) void msg_kernel(
    const float* __restrict__ P, const float* __restrict__ eks,
    const int* __restrict__ rps, float* __restrict__ msg, int m_lo, int m_cnt)
{
    int wv = blockIdx.x * 4 + (threadIdx.x >> 6);
    if (wv >= m_cnt) return;
    int i = m_lo + wv;
    int r0 = rps[i], r1 = rps[i + 1];
    if (r0 == r1) return;
    int l = threadIdx.x & 63;
    const float* Pr = P + (size_t)wv * PCOLS;
    float p[17];
#pragma unroll
    for (int k = 0; k < 17; ++k) p[k] = Pr[k * 64 + l];   // p[16] = bias block
    for (int s = r0; s < r1; ++s) {
        float ekv = eks[(size_t)s * 16 + (l & 15)];
        float m = p[16];
#pragma unroll
        for (int k = 0; k < 16; ++k) m = fmaf(__shfl(ekv, k, 64), p[k], m);
        msg[(size_t)s * 64 + l] = m;
    }
}

// ---------------- phase 2: per-dst sum + fused epilogue ----------------
__global__ __launch_bounds__(256) void agg_kernel(
    const float* __restrict__ msg, const int* __restrict__ slotidx,
    const int* __restrict__ rpd, const float* __restrict__ invd,
    const float* __restrict__ Proot, const float* __restrict__ convb,
    float* __restrict__ h, unsigned short* __restrict__ hhi,
    unsigned short* __restrict__ hlo)
{
    int i = blockIdx.x * 4 + (threadIdx.x >> 6);
    if (i >= NN) return;
    int l = threadIdx.x & 63;
    int r0 = rpd[i], r1 = rpd[i + 1];
    float acc = 0.f;
    for (int s = r0; s < r1; ++s) {
        int ss = slotidx[s];
        acc += msg[(size_t)ss * 64 + l];
    }
    float v = fmaf(acc, invd[i], Proot[(size_t)i * 64 + l] + convb[l]);
    v = fmaxf(v, 0.f);
    int idx = i * 64 + l;
    h[idx] = v;
    unsigned short hi = f2bf(v);
    hhi[idx] = hi;
    hlo[idx] = f2bf(v - bf2f(hi));
}

// ---------------- out = h @ fc2_w + fc2_b ----------------
__global__ __launch_bounds__(256) void out_kernel(
    const float* __restrict__ h, const float* __restrict__ fc2_w,
    const float* __restrict__ fc2_b, float* __restrict__ out)
{
    int wave = blockIdx.x * 4 + (threadIdx.x >> 6);
    int lane = threadIdx.x & 63;
    float v = h[(size_t)wave * 64 + lane] * fc2_w[lane];
#pragma unroll
    for (int off = 32; off > 0; off >>= 1) v += __shfl_down(v, off);
    if (lane == 0) out[wave] = v + fc2_b[0];
}

extern "C" void kernel_launch(void* const* d_in, const int* in_sizes, int n_in,
                              void* d_out, int out_size, void* d_ws, size_t ws_size,
                              hipStream_t stream)
{
    const float* x         = (const float*)d_in[0];
    const int*   ei        = (const int*)  d_in[1];
    const float* edge_attr = (const float*)d_in[2];
    const float* fc1_w     = (const float*)d_in[3];
    const float* fc1_b     = (const float*)d_in[4];
    const float* k1_w      = (const float*)d_in[5];
    const float* k1_b      = (const float*)d_in[6];
    const float* k2_w      = (const float*)d_in[7];
    const float* k2_b      = (const float*)d_in[8];
    const float* root_w    = (const float*)d_in[9];
    const float* conv_b    = (const float*)d_in[10];
    const float* fc2_w     = (const float*)d_in[11];
    const float* fc2_b     = (const float*)d_in[12];
    float* out = (float*)d_out;

    // workspace layout, f32 units
    float* ws = (float*)d_ws;
    size_t off = 0;
    int* cnt   = (int*)(ws + off); off += 4 * NN;       // outc|inc|fs|fd
    int* outc  = cnt;
    int* inc   = cnt + NN;
    int* fs    = cnt + 2 * NN;
    int* fd    = cnt + 3 * NN;
    int* rps   = (int*)(ws + off); off += 20004;
    int* rpd   = (int*)(ws + off); off += 20004;
    int* partials = (int*)(ws + off); off += 64;
    int* bases    = (int*)(ws + off); off += 64;
    int* slotidx = (int*)(ws + off); off += NE;
    float* invd  = ws + off; off += NN;
    float* eks   = ws + off; off += (size_t)NE * 16;
    unsigned short* Gh  = (unsigned short*)(ws + off); off += 36864;
    unsigned short* Gl  = (unsigned short*)(ws + off); off += 36864;
    unsigned short* hhi = (unsigned short*)(ws + off); off += (size_t)NN * 32;
    unsigned short* hlo = (unsigned short*)(ws + off); off += (size_t)NN * 32;
    float* h     = ws + off; off += (size_t)NN * WD;
    float* msg   = ws + off; off += (size_t)NE * WD;
    float* Proot = ws + off; off += (size_t)NN * WD;
    float* P     = ws + off;
    // full-P layout needs ~136 MB; halved ~92 MB.
    int halves = (ws_size >= (size_t)137000000) ? 1 : 2;
    int mchunk = NN / halves;

    hipMemsetAsync(cnt, 0, 4 * NN * sizeof(int), stream);
    count_kernel<<<(NE + 255) / 256, 256, 0, stream>>>(ei, outc, inc);
    scanA_kernel<<<40, 256, 0, stream>>>(cnt, partials);
    scanB_kernel<<<1, 64, 0, stream>>>(partials, bases);
    scanC_kernel<<<40, 256, 0, stream>>>(cnt, bases, rps, rpd, invd);
    ekfill_kernel<<<(NE + 255) / 256, 256, 0, stream>>>(ei, edge_attr, k1_w, k1_b,
                                                        rps, rpd, fs, fd, eks, slotidx);
    gwt_kernel<<<(1152 * 64 + 255) / 256, 256, 0, stream>>>(k2_w, k2_b, root_w, Gh, Gl);
    h0_kernel<<<(NN * WD + 255) / 256, 256, 0, stream>>>(x, fc1_w, fc1_b, hhi, hlo);

    for (int layer = 0; layer < DEPTH; ++layer) {
        for (int c = 0; c < halves; ++c) {
            int mlo = c * mchunk;
            int mtiles = mchunk / 16;
            int wv = mtiles * 18;
            gemm_kernel<<<(wv + 3) / 4, 256, 0, stream>>>(hhi, hlo, Gh, Gl, P,
                                                          Proot, mlo, mtiles);
            msg_kernel<<<(mchunk + 3) / 4, 256, 0, stream>>>(P, eks, rps, msg,
                                                             mlo, mchunk);
        }
        agg_kernel<<<(NN + 3) / 4, 256, 0, stream>>>(msg, slotidx, rpd, invd,
                                                     Proot, conv_b, h, hhi, hlo);
    }

    out_kernel<<<NN / 4, 256, 0, stream>>>(h, fc2_w, fc2_b, out);
}

// Round 4
// 694.323 us; speedup vs baseline: 1.3455x; 1.0567x over previous
//
#include <hip/hip_runtime.h>
#include <hip/hip_bf16.h>

// NNConv GNN, round 4:
//  Fused per-layer kernel: each workgroup owns a 12-node tile; computes
//  P_tile = h_tile @ [K_0..K_15|Bmat] via split-bf16 MFMA into LDS (52 KB,
//  never hits HBM), Proot strip to global, then runs the per-edge rank-17
//  combine out of LDS, scattering msg rows to dst-CSR slots so the agg pass
//  is a fully coalesced stream.
//  CSR built per call: count -> hierarchical 3-kernel scan -> fill.

#define NN 20000
#define NE 100000
#define WD 64
#define DEPTH 6
#define TM 12            // nodes per tile
#define LSTR 1092        // LDS row stride (floats); 1092 % 32 == 4 -> 2-way only

typedef __attribute__((ext_vector_type(8))) short bf16x8;
typedef __attribute__((ext_vector_type(4))) float f32x4;

__device__ __forceinline__ unsigned short f2bf(float v) {
    union { float f; unsigned u; } x; x.f = v;
    unsigned r = x.u + 0x7fffu + ((x.u >> 16) & 1u);
    return (unsigned short)(r >> 16);
}
__device__ __forceinline__ float bf2f(unsigned short b) {
    union { unsigned u; float f; } x; x.u = ((unsigned)b) << 16;
    return x.f;
}

// ---------------- per-node in/out degree counts ----------------
__global__ __launch_bounds__(256) void count_kernel(const int* __restrict__ ei,
                                                    int* __restrict__ outc,
                                                    int* __restrict__ inc)
{
    int e = blockIdx.x * 256 + threadIdx.x;
    if (e >= NE) return;
    atomicAdd(&outc[ei[e]], 1);
    atomicAdd(&inc[ei[NE + e]], 1);
}

// ---------------- hierarchical scan over [outc | inc] (40000 ints) ----------
__global__ __launch_bounds__(256) void scanA_kernel(const int* __restrict__ cnt,
                                                    int* __restrict__ partials)
{
    int b = blockIdx.x, t = threadIdx.x, lane = t & 63, w = t >> 6;
    int base = b * 1024 + t * 4;
    int s = 0;
#pragma unroll
    for (int i = 0; i < 4; ++i) {
        int idx = base + i;
        if (idx < 2 * NN) s += cnt[idx];
    }
#pragma unroll
    for (int off = 32; off > 0; off >>= 1) s += __shfl_down(s, off, 64);
    __shared__ int wsum[4];
    if (lane == 0) wsum[w] = s;
    __syncthreads();
    if (t == 0) partials[b] = wsum[0] + wsum[1] + wsum[2] + wsum[3];
}

__global__ __launch_bounds__(64) void scanB_kernel(const int* __restrict__ partials,
                                                   int* __restrict__ bases)
{
    int l = threadIdx.x;
    int p = (l < 40) ? partials[l] : 0;
    int v = p;
#pragma unroll
    for (int off = 1; off < 64; off <<= 1) {
        int u = __shfl_up(v, off, 64);
        if (l >= off) v += u;
    }
    if (l < 40) bases[l] = v - p;   // exclusive
}

__global__ __launch_bounds__(256) void scanC_kernel(const int* __restrict__ cnt,
                                                    const int* __restrict__ bases,
                                                    int* __restrict__ rps,
                                                    int* __restrict__ rpd,
                                                    float* __restrict__ invd)
{
    int b = blockIdx.x, t = threadIdx.x, lane = t & 63, w = t >> 6;
    int base = b * 1024 + t * 4;
    int v[4], s = 0;
#pragma unroll
    for (int i = 0; i < 4; ++i) {
        int idx = base + i;
        v[i] = (idx < 2 * NN) ? cnt[idx] : 0;
        s += v[i];
    }
    int tsum = s, sc = s;
#pragma unroll
    for (int off = 1; off < 64; off <<= 1) {
        int u = __shfl_up(sc, off, 64);
        if (lane >= off) sc += u;
    }
    __shared__ int wtot[4];
    if (lane == 63) wtot[w] = sc;
    __syncthreads();
    int wbase = 0;
    for (int j = 0; j < w; ++j) wbase += wtot[j];
    int run = bases[b] + wbase + sc - tsum;
#pragma unroll
    for (int i = 0; i < 4; ++i) {
        int idx = base + i;
        int e = run; run += v[i];
        if (idx < NN) {
            rps[idx] = e;
        } else if (idx < 2 * NN) {
            rpd[idx - NN] = e - NE;           // first-half total == NE
            invd[idx - NN] = 1.0f / fmaxf((float)v[i], 1.0f);
        }
    }
    if (b == 0 && t == 0) { rps[NN] = NE; rpd[NN] = NE; }
}

// ---------------- ek MLP + CSR fill; ss2sd maps src-slot -> dst-slot --------
__global__ __launch_bounds__(256) void ekfill_kernel(
    const int* __restrict__ ei, const float* __restrict__ ea,
    const float* __restrict__ k1w, const float* __restrict__ k1b,
    const int* __restrict__ rps, const int* __restrict__ rpd,
    int* __restrict__ fs, int* __restrict__ fd,
    float* __restrict__ eks, int* __restrict__ ss2sd)
{
    int e = blockIdx.x * 256 + threadIdx.x;
    if (e >= NE) return;
    int s = ei[e], d = ei[NE + e];
    float a[6];
#pragma unroll
    for (int i = 0; i < 6; ++i) a[i] = ea[e * 6 + i];
    int slot_s = rps[s] + atomicAdd(&fs[s], 1);
    int slot_d = rpd[d] + atomicAdd(&fd[d], 1);
    ss2sd[slot_s] = slot_d;
#pragma unroll
    for (int j = 0; j < 16; ++j) {
        float v = k1b[j];
#pragma unroll
        for (int i = 0; i < 6; ++i) v = fmaf(a[i], k1w[i * 16 + j], v);
        eks[(size_t)slot_s * 16 + j] = fmaxf(v, 0.f);
    }
}

// ---------------- GwT hi/lo bf16, [1152 rows n][64 cols k] -----------------
__global__ __launch_bounds__(256) void gwt_kernel(
    const float* __restrict__ k2w, const float* __restrict__ k2b,
    const float* __restrict__ rootw,
    unsigned short* __restrict__ Gh, unsigned short* __restrict__ Gl)
{
    int idx = blockIdx.x * 256 + threadIdx.x;   // 1152*64
    if (idx >= 1152 * 64) return;
    int n = idx >> 6, k = idx & 63;
    int b = n >> 6, o = n & 63;
    float g;
    if (b < 16)       g = k2w[b * 4096 + k * 64 + o];
    else if (b == 16) g = k2b[k * 64 + o];
    else              g = rootw[k * 64 + o];
    unsigned short hi = f2bf(g);
    Gh[idx] = hi;
    Gl[idx] = f2bf(g - bf2f(hi));
}

// ---------------- h0 = x*fc1_w + fc1_b -> hi/lo bf16 ----------------
__global__ __launch_bounds__(256) void h0_kernel(
    const float* __restrict__ x, const float* __restrict__ w,
    const float* __restrict__ b,
    unsigned short* __restrict__ hhi, unsigned short* __restrict__ hlo)
{
    int idx = blockIdx.x * 256 + threadIdx.x;
    if (idx >= NN * WD) return;
    int n = idx >> 6, o = idx & 63;
    float v = fmaf(x[n], w[o], b[o]);
    unsigned short hi = f2bf(v);
    hhi[idx] = hi;
    hlo[idx] = f2bf(v - bf2f(hi));
}

// ---------------- fused GEMM (P->LDS, Proot->global) + edge msg -------------
// block = 4 waves, tile = 12 nodes. Strips 0..16 -> LDS Pt; strip 17 -> Proot.
__global__ __launch_bounds__(256) void gemmsg_kernel(
    const unsigned short* __restrict__ hhi, const unsigned short* __restrict__ hlo,
    const unsigned short* __restrict__ Gh, const unsigned short* __restrict__ Gl,
    const float* __restrict__ eks, const int* __restrict__ ss2sd,
    const int* __restrict__ rps, float* __restrict__ Proot,
    float* __restrict__ msg)
{
    __shared__ float Pt[TM * LSTR];   // 52,416 B
    int n0 = blockIdx.x * TM;
    int w = threadIdx.x >> 6, l = threadIdx.x & 63;
    int quad = l >> 4, lr = l & 15;
    int arow = n0 + lr;
    if (arow > NN - 1) arow = NN - 1;
    const bf16x8* pah = (const bf16x8*)(hhi + (size_t)arow * 64 + quad * 8);
    const bf16x8* pal = (const bf16x8*)(hlo + (size_t)arow * 64 + quad * 8);
    bf16x8 ah0 = pah[0], ah1 = pah[4];   // k 0..31, 32..63
    bf16x8 al0 = pal[0], al1 = pal[4];

    for (int st = w; st < 18; st += 4) {
        f32x4 acc[4];
#pragma unroll
        for (int t = 0; t < 4; ++t) acc[t] = (f32x4){0.f, 0.f, 0.f, 0.f};
#pragma unroll
        for (int t = 0; t < 4; ++t) {
            int brow = st * 64 + t * 16 + lr;
            const bf16x8* pbh = (const bf16x8*)(Gh + (size_t)brow * 64 + quad * 8);
            const bf16x8* pbl = (const bf16x8*)(Gl + (size_t)brow * 64 + quad * 8);
            bf16x8 bh0 = pbh[0], bh1 = pbh[4];
            bf16x8 bl0 = pbl[0], bl1 = pbl[4];
            f32x4 a = acc[t];
            a = __builtin_amdgcn_mfma_f32_16x16x32_bf16(ah0, bh0, a, 0, 0, 0);
            a = __builtin_amdgcn_mfma_f32_16x16x32_bf16(ah0, bl0, a, 0, 0, 0);
            a = __builtin_amdgcn_mfma_f32_16x16x32_bf16(al0, bh0, a, 0, 0, 0);
            a = __builtin_amdgcn_mfma_f32_16x16x32_bf16(ah1, bh1, a, 0, 0, 0);
            a = __builtin_amdgcn_mfma_f32_16x16x32_bf16(ah1, bl1, a, 0, 0, 0);
            a = __builtin_amdgcn_mfma_f32_16x16x32_bf16(al1, bh1, a, 0, 0, 0);
            acc[t] = a;
        }
        // C/D: col = lane&15, row = quad*4 + reg
        if (st < 17) {
#pragma unroll
            for (int t = 0; t < 4; ++t)
#pragma unroll
                for (int r = 0; r < 4; ++r) {
                    int row = quad * 4 + r;
                    if (row < TM)
                        Pt[row * LSTR + st * 64 + t * 16 + lr] = acc[t][r];
                }
        } else {
#pragma unroll
            for (int t = 0; t < 4; ++t)
#pragma unroll
                for (int r = 0; r < 4; ++r) {
                    int row = quad * 4 + r;
                    int gn = n0 + row;
                    if (row < TM && gn < NN)
                        Proot[(size_t)gn * 64 + t * 16 + lr] = acc[t][r];
                }
        }
    }
    __syncthreads();

    // edge phase: wave w handles local nodes w, w+4, w+8
#pragma unroll
    for (int j = 0; j < 3; ++j) {
        int ln = w + 4 * j;
        int gn = n0 + ln;
        if (gn >= NN) break;
        int r0 = rps[gn], r1 = rps[gn + 1];
        if (r0 == r1) continue;
        float p[17];
#pragma unroll
        for (int k = 0; k < 17; ++k) p[k] = Pt[ln * LSTR + k * 64 + l];
        for (int s = r0; s < r1; ++s) {
            float ekv = eks[(size_t)s * 16 + (l & 15)];
            int ds = ss2sd[s];
            float m = p[16];
#pragma unroll
            for (int k = 0; k < 16; ++k) m = fmaf(__shfl(ekv, k, 64), p[k], m);
            msg[(size_t)ds * 64 + l] = m;
        }
    }
}

// ---------------- per-dst sum (coalesced) + fused epilogue ----------------
__global__ __launch_bounds__(256) void agg_kernel(
    const float* __restrict__ msg, const int* __restrict__ rpd,
    const float* __restrict__ invd, const float* __restrict__ Proot,
    const float* __restrict__ convb, float* __restrict__ h,
    unsigned short* __restrict__ hhi, unsigned short* __restrict__ hlo)
{
    int i = blockIdx.x * 4 + (threadIdx.x >> 6);
    if (i >= NN) return;
    int l = threadIdx.x & 63;
    int r0 = rpd[i], r1 = rpd[i + 1];
    float acc = 0.f;
    for (int s = r0; s < r1; ++s) acc += msg[(size_t)s * 64 + l];
    float v = fmaf(acc, invd[i], Proot[(size_t)i * 64 + l] + convb[l]);
    v = fmaxf(v, 0.f);
    int idx = i * 64 + l;
    h[idx] = v;
    unsigned short hi = f2bf(v);
    hhi[idx] = hi;
    hlo[idx] = f2bf(v - bf2f(hi));
}

// ---------------- out = h @ fc2_w + fc2_b ----------------
__global__ __launch_bounds__(256) void out_kernel(
    const float* __restrict__ h, const float* __restrict__ fc2_w,
    const float* __restrict__ fc2_b, float* __restrict__ out)
{
    int wave = blockIdx.x * 4 + (threadIdx.x >> 6);
    int lane = threadIdx.x & 63;
    float v = h[(size_t)wave * 64 + lane] * fc2_w[lane];
#pragma unroll
    for (int off = 32; off > 0; off >>= 1) v += __shfl_down(v, off);
    if (lane == 0) out[wave] = v + fc2_b[0];
}

extern "C" void kernel_launch(void* const* d_in, const int* in_sizes, int n_in,
                              void* d_out, int out_size, void* d_ws, size_t ws_size,
                              hipStream_t stream)
{
    const float* x         = (const float*)d_in[0];
    const int*   ei        = (const int*)  d_in[1];
    const float* edge_attr = (const float*)d_in[2];
    const float* fc1_w     = (const float*)d_in[3];
    const float* fc1_b     = (const float*)d_in[4];
    const float* k1_w      = (const float*)d_in[5];
    const float* k1_b      = (const float*)d_in[6];
    const float* k2_w      = (const float*)d_in[7];
    const float* k2_b      = (const float*)d_in[8];
    const float* root_w    = (const float*)d_in[9];
    const float* conv_b    = (const float*)d_in[10];
    const float* fc2_w     = (const float*)d_in[11];
    const float* fc2_b     = (const float*)d_in[12];
    float* out = (float*)d_out;

    // workspace layout, f32 units
    float* ws = (float*)d_ws;
    size_t off = 0;
    int* cnt   = (int*)(ws + off); off += 4 * NN;       // outc|inc|fs|fd
    int* outc  = cnt;
    int* inc   = cnt + NN;
    int* fs    = cnt + 2 * NN;
    int* fd    = cnt + 3 * NN;
    int* rps   = (int*)(ws + off); off += 20004;
    int* rpd   = (int*)(ws + off); off += 20004;
    int* partials = (int*)(ws + off); off += 64;
    int* bases    = (int*)(ws + off); off += 64;
    int* ss2sd = (int*)(ws + off); off += NE;
    float* invd  = ws + off; off += NN;
    float* eks   = ws + off; off += (size_t)NE * 16;
    unsigned short* Gh  = (unsigned short*)(ws + off); off += 36864;
    unsigned short* Gl  = (unsigned short*)(ws + off); off += 36864;
    unsigned short* hhi = (unsigned short*)(ws + off); off += (size_t)NN * 32;
    unsigned short* hlo = (unsigned short*)(ws + off); off += (size_t)NN * 32;
    float* h     = ws + off; off += (size_t)NN * WD;
    float* msg   = ws + off; off += (size_t)NE * WD;
    float* Proot = ws + off; off += (size_t)NN * WD;

    hipMemsetAsync(cnt, 0, 4 * NN * sizeof(int), stream);
    count_kernel<<<(NE + 255) / 256, 256, 0, stream>>>(ei, outc, inc);
    scanA_kernel<<<40, 256, 0, stream>>>(cnt, partials);
    scanB_kernel<<<1, 64, 0, stream>>>(partials, bases);
    scanC_kernel<<<40, 256, 0, stream>>>(cnt, bases, rps, rpd, invd);
    ekfill_kernel<<<(NE + 255) / 256, 256, 0, stream>>>(ei, edge_attr, k1_w, k1_b,
                                                        rps, rpd, fs, fd, eks, ss2sd);
    gwt_kernel<<<(1152 * 64 + 255) / 256, 256, 0, stream>>>(k2_w, k2_b, root_w, Gh, Gl);
    h0_kernel<<<(NN * WD + 255) / 256, 256, 0, stream>>>(x, fc1_w, fc1_b, hhi, hlo);

    int ntiles = (NN + TM - 1) / TM;   // 1667
    for (int layer = 0; layer < DEPTH; ++layer) {
        gemmsg_kernel<<<ntiles, 256, 0, stream>>>(hhi, hlo, Gh, Gl, eks, ss2sd,
                                                  rps, Proot, msg);
        agg_kernel<<<(NN + 3) / 4, 256, 0, stream>>>(msg, rpd, invd, Proot,
                                                     conv_b, h, hhi, hlo);
    }

    out_kernel<<<NN / 4, 256, 0, stream>>>(h, fc2_w, fc2_b, out);
}

// Round 5
// 682.445 us; speedup vs baseline: 1.3689x; 1.0174x over previous
//
#include <hip/hip_runtime.h>
#include <hip/hip_bf16.h>

// NNConv GNN, round 5:
//  Split structure (R3) with fixed GEMM stores:
//  P = h @ [K_0..K_15|Bmat] and Proot = h @ root_w in ONE split-bf16 MFMA GEMM
//  (18 n-strips). Each wave transposes its 16x64 C tile through LDS so global
//  stores are dwordx4 with 256B-1KB contiguous segments (R3 was 64B-segmented
//  dword stores -> 1.45 TB/s write-bound).
//  Edge phase: per-src msg pass (P row in regs, 2x-unrolled edge loop,
//  scatters to dst-CSR slots via ss2sd) then coalesced per-dst agg pass with
//  fused mean/root/bias/relu epilogue.
//  CSR built per call: count -> hierarchical 3-kernel scan -> fill.

#define NN 20000
#define NE 100000
#define WD 64
#define PCOLS 1088      // 16 K-blocks + bias block (root strip separate)
#define DEPTH 6
#define TSTR 68         // LDS transpose row stride (words): writes 2-way, reads 4-way

typedef __attribute__((ext_vector_type(8))) short bf16x8;
typedef __attribute__((ext_vector_type(4))) float f32x4;

__device__ __forceinline__ unsigned short f2bf(float v) {
    union { float f; unsigned u; } x; x.f = v;
    unsigned r = x.u + 0x7fffu + ((x.u >> 16) & 1u);
    return (unsigned short)(r >> 16);
}
__device__ __forceinline__ float bf2f(unsigned short b) {
    union { unsigned u; float f; } x; x.u = ((unsigned)b) << 16;
    return x.f;
}

// ---------------- per-node in/out degree counts ----------------
__global__ __launch_bounds__(256) void count_kernel(const int* __restrict__ ei,
                                                    int* __restrict__ outc,
                                                    int* __restrict__ inc)
{
    int e = blockIdx.x * 256 + threadIdx.x;
    if (e >= NE) return;
    atomicAdd(&outc[ei[e]], 1);
    atomicAdd(&inc[ei[NE + e]], 1);
}

// ---------------- hierarchical scan over [outc | inc] (40000 ints) ----------
__global__ __launch_bounds__(256) void scanA_kernel(const int* __restrict__ cnt,
                                                    int* __restrict__ partials)
{
    int b = blockIdx.x, t = threadIdx.x, lane = t & 63, w = t >> 6;
    int base = b * 1024 + t * 4;
    int s = 0;
#pragma unroll
    for (int i = 0; i < 4; ++i) {
        int idx = base + i;
        if (idx < 2 * NN) s += cnt[idx];
    }
#pragma unroll
    for (int off = 32; off > 0; off >>= 1) s += __shfl_down(s, off, 64);
    __shared__ int wsum[4];
    if (lane == 0) wsum[w] = s;
    __syncthreads();
    if (t == 0) partials[b] = wsum[0] + wsum[1] + wsum[2] + wsum[3];
}

__global__ __launch_bounds__(64) void scanB_kernel(const int* __restrict__ partials,
                                                   int* __restrict__ bases)
{
    int l = threadIdx.x;
    int p = (l < 40) ? partials[l] : 0;
    int v = p;
#pragma unroll
    for (int off = 1; off < 64; off <<= 1) {
        int u = __shfl_up(v, off, 64);
        if (l >= off) v += u;
    }
    if (l < 40) bases[l] = v - p;   // exclusive
}

__global__ __launch_bounds__(256) void scanC_kernel(const int* __restrict__ cnt,
                                                    const int* __restrict__ bases,
                                                    int* __restrict__ rps,
                                                    int* __restrict__ rpd,
                                                    float* __restrict__ invd)
{
    int b = blockIdx.x, t = threadIdx.x, lane = t & 63, w = t >> 6;
    int base = b * 1024 + t * 4;
    int v[4], s = 0;
#pragma unroll
    for (int i = 0; i < 4; ++i) {
        int idx = base + i;
        v[i] = (idx < 2 * NN) ? cnt[idx] : 0;
        s += v[i];
    }
    int tsum = s, sc = s;
#pragma unroll
    for (int off = 1; off < 64; off <<= 1) {
        int u = __shfl_up(sc, off, 64);
        if (lane >= off) sc += u;
    }
    __shared__ int wtot[4];
    if (lane == 63) wtot[w] = sc;
    __syncthreads();
    int wbase = 0;
    for (int j = 0; j < w; ++j) wbase += wtot[j];
    int run = bases[b] + wbase + sc - tsum;
#pragma unroll
    for (int i = 0; i < 4; ++i) {
        int idx = base + i;
        int e = run; run += v[i];
        if (idx < NN) {
            rps[idx] = e;
        } else if (idx < 2 * NN) {
            rpd[idx - NN] = e - NE;           // first-half total == NE
            invd[idx - NN] = 1.0f / fmaxf((float)v[i], 1.0f);
        }
    }
    if (b == 0 && t == 0) { rps[NN] = NE; rpd[NN] = NE; }
}

// ---------------- ek MLP + CSR fill; ss2sd maps src-slot -> dst-slot --------
__global__ __launch_bounds__(256) void ekfill_kernel(
    const int* __restrict__ ei, const float* __restrict__ ea,
    const float* __restrict__ k1w, const float* __restrict__ k1b,
    const int* __restrict__ rps, const int* __restrict__ rpd,
    int* __restrict__ fs, int* __restrict__ fd,
    float* __restrict__ eks, int* __restrict__ ss2sd)
{
    int e = blockIdx.x * 256 + threadIdx.x;
    if (e >= NE) return;
    int s = ei[e], d = ei[NE + e];
    float a[6];
#pragma unroll
    for (int i = 0; i < 6; ++i) a[i] = ea[e * 6 + i];
    int slot_s = rps[s] + atomicAdd(&fs[s], 1);
    int slot_d = rpd[d] + atomicAdd(&fd[d], 1);
    ss2sd[slot_s] = slot_d;
#pragma unroll
    for (int j = 0; j < 16; ++j) {
        float v = k1b[j];
#pragma unroll
        for (int i = 0; i < 6; ++i) v = fmaf(a[i], k1w[i * 16 + j], v);
        eks[(size_t)slot_s * 16 + j] = fmaxf(v, 0.f);
    }
}

// ---------------- GwT hi/lo bf16, [1152 rows n][64 cols k] -----------------
__global__ __launch_bounds__(256) void gwt_kernel(
    const float* __restrict__ k2w, const float* __restrict__ k2b,
    const float* __restrict__ rootw,
    unsigned short* __restrict__ Gh, unsigned short* __restrict__ Gl)
{
    int idx = blockIdx.x * 256 + threadIdx.x;   // 1152*64
    if (idx >= 1152 * 64) return;
    int n = idx >> 6, k = idx & 63;
    int b = n >> 6, o = n & 63;
    float g;
    if (b < 16)       g = k2w[b * 4096 + k * 64 + o];
    else if (b == 16) g = k2b[k * 64 + o];
    else              g = rootw[k * 64 + o];
    unsigned short hi = f2bf(g);
    Gh[idx] = hi;
    Gl[idx] = f2bf(g - bf2f(hi));
}

// ---------------- h0 = x*fc1_w + fc1_b -> hi/lo bf16 ----------------
__global__ __launch_bounds__(256) void h0_kernel(
    const float* __restrict__ x, const float* __restrict__ w,
    const float* __restrict__ b,
    unsigned short* __restrict__ hhi, unsigned short* __restrict__ hlo)
{
    int idx = blockIdx.x * 256 + threadIdx.x;
    if (idx >= NN * WD) return;
    int n = idx >> 6, o = idx & 63;
    float v = fmaf(x[n], w[o], b[o]);
    unsigned short hi = f2bf(v);
    hhi[idx] = hi;
    hlo[idx] = f2bf(v - bf2f(hi));
}

// ---------------- split-bf16 MFMA GEMM, 18 strips, LDS-transposed stores ----
// wave tile: 16m x 64n, K=64, 6 MFMAs per 16x16 n-tile. C tile goes through a
// per-wave LDS transpose so global stores are dwordx4 (4 rows x 256B / instr).
__global__ __launch_bounds__(256) void gemm_kernel(
    const unsigned short* __restrict__ hhi, const unsigned short* __restrict__ hlo,
    const unsigned short* __restrict__ Gh, const unsigned short* __restrict__ Gl,
    float* __restrict__ P, float* __restrict__ Proot, int m_lo, int m_tiles)
{
    __shared__ __align__(16) float Tr[4][16 * TSTR];   // 4 x 4352B
    int wid = blockIdx.x * 4 + (threadIdx.x >> 6);
    if (wid >= m_tiles * 18) return;                   // no barriers below
    int w = threadIdx.x >> 6;
    int mt = wid % m_tiles, st = wid / m_tiles;
    int l = threadIdx.x & 63;
    int quad = l >> 4, lr = l & 15;
    int arow = m_lo + mt * 16 + lr;
    const bf16x8* pah = (const bf16x8*)(hhi + (size_t)arow * 64 + quad * 8);
    const bf16x8* pal = (const bf16x8*)(hlo + (size_t)arow * 64 + quad * 8);
    bf16x8 ah0 = pah[0], ah1 = pah[4];   // k 0..31, 32..63
    bf16x8 al0 = pal[0], al1 = pal[4];
    f32x4 acc[4];
#pragma unroll
    for (int t = 0; t < 4; ++t) acc[t] = (f32x4){0.f, 0.f, 0.f, 0.f};
#pragma unroll
    for (int t = 0; t < 4; ++t) {
        int brow = st * 64 + t * 16 + lr;
        const bf16x8* pbh = (const bf16x8*)(Gh + (size_t)brow * 64 + quad * 8);
        const bf16x8* pbl = (const bf16x8*)(Gl + (size_t)brow * 64 + quad * 8);
        bf16x8 bh0 = pbh[0], bh1 = pbh[4];
        bf16x8 bl0 = pbl[0], bl1 = pbl[4];
        f32x4 a = acc[t];
        a = __builtin_amdgcn_mfma_f32_16x16x32_bf16(ah0, bh0, a, 0, 0, 0);
        a = __builtin_amdgcn_mfma_f32_16x16x32_bf16(ah0, bl0, a, 0, 0, 0);
        a = __builtin_amdgcn_mfma_f32_16x16x32_bf16(al0, bh0, a, 0, 0, 0);
        a = __builtin_amdgcn_mfma_f32_16x16x32_bf16(ah1, bh1, a, 0, 0, 0);
        a = __builtin_amdgcn_mfma_f32_16x16x32_bf16(ah1, bl1, a, 0, 0, 0);
        a = __builtin_amdgcn_mfma_f32_16x16x32_bf16(al1, bh1, a, 0, 0, 0);
        acc[t] = a;
    }
    // C/D layout: col = lane&15, row = quad*4 + reg  ->  LDS T[row][col]
    float* T = &Tr[w][0];
#pragma unroll
    for (int t = 0; t < 4; ++t)
#pragma unroll
        for (int r = 0; r < 4; ++r)
            T[(quad * 4 + r) * TSTR + t * 16 + lr] = acc[t][r];
    // read back row-major: lane -> (row = ir*4+quad, cols 4*lr..4*lr+3)
    int gm0 = m_lo + mt * 16;
#pragma unroll
    for (int ir = 0; ir < 4; ++ir) {
        int row = ir * 4 + quad;
        f32x4 v = *(const f32x4*)&T[row * TSTR + 4 * lr];
        if (st < 17)
            *(f32x4*)&P[(size_t)(gm0 - m_lo + row) * PCOLS + st * 64 + 4 * lr] = v;
        else
            *(f32x4*)&Proot[(size_t)(gm0 + row) * 64 + 4 * lr] = v;
    }
}

// ---------------- phase 1: per-src msg, P row in registers, 2x unroll -------
__global__ __launch_bounds__(256) void msg_kernel(
    const float* __restrict__ P, const float* __restrict__ eks,
    const int* __restrict__ ss2sd, const int* __restrict__ rps,
    float* __restrict__ msg, int m_lo, int m_cnt)
{
    int wv = blockIdx.x * 4 + (threadIdx.x >> 6);
    if (wv >= m_cnt) return;
    int i = m_lo + wv;
    int r0 = rps[i], r1 = rps[i + 1];
    if (r0 == r1) return;
    int l = threadIdx.x & 63;
    const float* Pr = P + (size_t)wv * PCOLS;
    float p[17];
#pragma unroll
    for (int k = 0; k < 17; ++k) p[k] = Pr[k * 64 + l];   // p[16] = bias block
    int s = r0;
    for (; s + 1 < r1; s += 2) {
        float e0 = eks[(size_t)s * 16 + (l & 15)];
        float e1 = eks[(size_t)(s + 1) * 16 + (l & 15)];
        int d0 = ss2sd[s], d1 = ss2sd[s + 1];
        float m0 = p[16], m1 = p[16];
#pragma unroll
        for (int k = 0; k < 16; ++k) {
            m0 = fmaf(__shfl(e0, k, 64), p[k], m0);
            m1 = fmaf(__shfl(e1, k, 64), p[k], m1);
        }
        msg[(size_t)d0 * 64 + l] = m0;
        msg[(size_t)d1 * 64 + l] = m1;
    }
    if (s < r1) {
        float e0 = eks[(size_t)s * 16 + (l & 15)];
        int d0 = ss2sd[s];
        float m0 = p[16];
#pragma unroll
        for (int k = 0; k < 16; ++k) m0 = fmaf(__shfl(e0, k, 64), p[k], m0);
        msg[(size_t)d0 * 64 + l] = m0;
    }
}

// ---------------- phase 2: per-dst sum (coalesced) + fused epilogue ---------
__global__ __launch_bounds__(256) void agg_kernel(
    const float* __restrict__ msg, const int* __restrict__ rpd,
    const float* __restrict__ invd, const float* __restrict__ Proot,
    const float* __restrict__ convb, float* __restrict__ h,
    unsigned short* __restrict__ hhi, unsigned short* __restrict__ hlo)
{
    int i = blockIdx.x * 4 + (threadIdx.x >> 6);
    if (i >= NN) return;
    int l = threadIdx.x & 63;
    int r0 = rpd[i], r1 = rpd[i + 1];
    float acc = 0.f;
    for (int s = r0; s < r1; ++s) acc += msg[(size_t)s * 64 + l];
    float v = fmaf(acc, invd[i], Proot[(size_t)i * 64 + l] + convb[l]);
    v = fmaxf(v, 0.f);
    int idx = i * 64 + l;
    h[idx] = v;
    unsigned short hi = f2bf(v);
    hhi[idx] = hi;
    hlo[idx] = f2bf(v - bf2f(hi));
}

// ---------------- out = h @ fc2_w + fc2_b ----------------
__global__ __launch_bounds__(256) void out_kernel(
    const float* __restrict__ h, const float* __restrict__ fc2_w,
    const float* __restrict__ fc2_b, float* __restrict__ out)
{
    int wave = blockIdx.x * 4 + (threadIdx.x >> 6);
    int lane = threadIdx.x & 63;
    float v = h[(size_t)wave * 64 + lane] * fc2_w[lane];
#pragma unroll
    for (int off = 32; off > 0; off >>= 1) v += __shfl_down(v, off);
    if (lane == 0) out[wave] = v + fc2_b[0];
}

extern "C" void kernel_launch(void* const* d_in, const int* in_sizes, int n_in,
                              void* d_out, int out_size, void* d_ws, size_t ws_size,
                              hipStream_t stream)
{
    const float* x         = (const float*)d_in[0];
    const int*   ei        = (const int*)  d_in[1];
    const float* edge_attr = (const float*)d_in[2];
    const float* fc1_w     = (const float*)d_in[3];
    const float* fc1_b     = (const float*)d_in[4];
    const float* k1_w      = (const float*)d_in[5];
    const float* k1_b      = (const float*)d_in[6];
    const float* k2_w      = (const float*)d_in[7];
    const float* k2_b      = (const float*)d_in[8];
    const float* root_w    = (const float*)d_in[9];
    const float* conv_b    = (const float*)d_in[10];
    const float* fc2_w     = (const float*)d_in[11];
    const float* fc2_b     = (const float*)d_in[12];
    float* out = (float*)d_out;

    // workspace layout, f32 units
    float* ws = (float*)d_ws;
    size_t off = 0;
    int* cnt   = (int*)(ws + off); off += 4 * NN;       // outc|inc|fs|fd
    int* outc  = cnt;
    int* inc   = cnt + NN;
    int* fs    = cnt + 2 * NN;
    int* fd    = cnt + 3 * NN;
    int* rps   = (int*)(ws + off); off += 20004;
    int* rpd   = (int*)(ws + off); off += 20004;
    int* partials = (int*)(ws + off); off += 64;
    int* bases    = (int*)(ws + off); off += 64;
    int* ss2sd = (int*)(ws + off); off += NE;
    float* invd  = ws + off; off += NN;
    float* eks   = ws + off; off += (size_t)NE * 16;
    unsigned short* Gh  = (unsigned short*)(ws + off); off += 36864;
    unsigned short* Gl  = (unsigned short*)(ws + off); off += 36864;
    unsigned short* hhi = (unsigned short*)(ws + off); off += (size_t)NN * 32;
    unsigned short* hlo = (unsigned short*)(ws + off); off += (size_t)NN * 32;
    float* h     = ws + off; off += (size_t)NN * WD;
    float* msg   = ws + off; off += (size_t)NE * WD;
    float* Proot = ws + off; off += (size_t)NN * WD;
    float* P     = ws + off;
    // full-P layout needs ~136 MB; halved ~92 MB.
    int halves = (ws_size >= (size_t)137000000) ? 1 : 2;
    int mchunk = NN / halves;

    hipMemsetAsync(cnt, 0, 4 * NN * sizeof(int), stream);
    count_kernel<<<(NE + 255) / 256, 256, 0, stream>>>(ei, outc, inc);
    scanA_kernel<<<40, 256, 0, stream>>>(cnt, partials);
    scanB_kernel<<<1, 64, 0, stream>>>(partials, bases);
    scanC_kernel<<<40, 256, 0, stream>>>(cnt, bases, rps, rpd, invd);
    ekfill_kernel<<<(NE + 255) / 256, 256, 0, stream>>>(ei, edge_attr, k1_w, k1_b,
                                                        rps, rpd, fs, fd, eks, ss2sd);
    gwt_kernel<<<(1152 * 64 + 255) / 256, 256, 0, stream>>>(k2_w, k2_b, root_w, Gh, Gl);
    h0_kernel<<<(NN * WD + 255) / 256, 256, 0, stream>>>(x, fc1_w, fc1_b, hhi, hlo);

    for (int layer = 0; layer < DEPTH; ++layer) {
        for (int c = 0; c < halves; ++c) {
            int mlo = c * mchunk;
            int mtiles = mchunk / 16;
            int wv = mtiles * 18;
            gemm_kernel<<<(wv + 3) / 4, 256, 0, stream>>>(hhi, hlo, Gh, Gl, P,
                                                          Proot, mlo, mtiles);
            msg_kernel<<<(mchunk + 3) / 4, 256, 0, stream>>>(P, eks, ss2sd, rps,
                                                             msg, mlo, mchunk);
        }
        agg_kernel<<<(NN + 3) / 4, 256, 0, stream>>>(msg, rpd, invd, Proot,
                                                     conv_b, h, hhi, hlo);
    }

    out_kernel<<<NN / 4, 256, 0, stream>>>(h, fc2_w, fc2_b, out);
}

// Round 6
// 628.228 us; speedup vs baseline: 1.4871x; 1.0863x over previous
//
#include <hip/hip_runtime.h>
#include <hip/hip_bf16.h>

// NNConv GNN, round 6:
//  Fully fused per-layer kernel (R4 concept, fixed): 512-thread blocks own a
//  15-node tile. 8 waves compute P_tile = h_tile @ [K_0..K_15|Bmat] via
//  split-bf16 MFMA into LDS (65,520 B; P never touches HBM) + Proot strip to
//  global; then all 8 waves stride the tile's contiguous src-CSR slot range
//  (balanced regardless of per-node degree), doing the rank-17 combine from
//  LDS and scattering msg rows to dst-CSR order for the coalesced agg pass.
//  CSR built per call: count -> hierarchical 3-kernel scan -> fill.

#define NN 20000
#define NE 100000
#define WD 64
#define DEPTH 6
#define TM 15            // nodes per tile (row 15 of the MFMA tile wasted)
#define LSTR 1092        // LDS row stride (words): 1092%32==4 -> 2-way only

typedef __attribute__((ext_vector_type(8))) short bf16x8;
typedef __attribute__((ext_vector_type(4))) float f32x4;

__device__ __forceinline__ unsigned short f2bf(float v) {
    union { float f; unsigned u; } x; x.f = v;
    unsigned r = x.u + 0x7fffu + ((x.u >> 16) & 1u);
    return (unsigned short)(r >> 16);
}
__device__ __forceinline__ float bf2f(unsigned short b) {
    union { unsigned u; float f; } x; x.u = ((unsigned)b) << 16;
    return x.f;
}

// ---------------- per-node in/out degree counts ----------------
__global__ __launch_bounds__(256) void count_kernel(const int* __restrict__ ei,
                                                    int* __restrict__ outc,
                                                    int* __restrict__ inc)
{
    int e = blockIdx.x * 256 + threadIdx.x;
    if (e >= NE) return;
    atomicAdd(&outc[ei[e]], 1);
    atomicAdd(&inc[ei[NE + e]], 1);
}

// ---------------- hierarchical scan over [outc | inc] (40000 ints) ----------
__global__ __launch_bounds__(256) void scanA_kernel(const int* __restrict__ cnt,
                                                    int* __restrict__ partials)
{
    int b = blockIdx.x, t = threadIdx.x, lane = t & 63, w = t >> 6;
    int base = b * 1024 + t * 4;
    int s = 0;
#pragma unroll
    for (int i = 0; i < 4; ++i) {
        int idx = base + i;
        if (idx < 2 * NN) s += cnt[idx];
    }
#pragma unroll
    for (int off = 32; off > 0; off >>= 1) s += __shfl_down(s, off, 64);
    __shared__ int wsum[4];
    if (lane == 0) wsum[w] = s;
    __syncthreads();
    if (t == 0) partials[b] = wsum[0] + wsum[1] + wsum[2] + wsum[3];
}

__global__ __launch_bounds__(64) void scanB_kernel(const int* __restrict__ partials,
                                                   int* __restrict__ bases)
{
    int l = threadIdx.x;
    int p = (l < 40) ? partials[l] : 0;
    int v = p;
#pragma unroll
    for (int off = 1; off < 64; off <<= 1) {
        int u = __shfl_up(v, off, 64);
        if (l >= off) v += u;
    }
    if (l < 40) bases[l] = v - p;   // exclusive
}

__global__ __launch_bounds__(256) void scanC_kernel(const int* __restrict__ cnt,
                                                    const int* __restrict__ bases,
                                                    int* __restrict__ rps,
                                                    int* __restrict__ rpd,
                                                    float* __restrict__ invd)
{
    int b = blockIdx.x, t = threadIdx.x, lane = t & 63, w = t >> 6;
    int base = b * 1024 + t * 4;
    int v[4], s = 0;
#pragma unroll
    for (int i = 0; i < 4; ++i) {
        int idx = base + i;
        v[i] = (idx < 2 * NN) ? cnt[idx] : 0;
        s += v[i];
    }
    int tsum = s, sc = s;
#pragma unroll
    for (int off = 1; off < 64; off <<= 1) {
        int u = __shfl_up(sc, off, 64);
        if (lane >= off) sc += u;
    }
    __shared__ int wtot[4];
    if (lane == 63) wtot[w] = sc;
    __syncthreads();
    int wbase = 0;
    for (int j = 0; j < w; ++j) wbase += wtot[j];
    int run = bases[b] + wbase + sc - tsum;
#pragma unroll
    for (int i = 0; i < 4; ++i) {
        int idx = base + i;
        int e = run; run += v[i];
        if (idx < NN) {
            rps[idx] = e;
        } else if (idx < 2 * NN) {
            rpd[idx - NN] = e - NE;           // first-half total == NE
            invd[idx - NN] = 1.0f / fmaxf((float)v[i], 1.0f);
        }
    }
    if (b == 0 && t == 0) { rps[NN] = NE; rpd[NN] = NE; }
}

// ---------------- ek MLP + CSR fill ----------------
__global__ __launch_bounds__(256) void ekfill_kernel(
    const int* __restrict__ ei, const float* __restrict__ ea,
    const float* __restrict__ k1w, const float* __restrict__ k1b,
    const int* __restrict__ rps, const int* __restrict__ rpd,
    int* __restrict__ fs, int* __restrict__ fd,
    float* __restrict__ eks, int* __restrict__ ss2sd,
    int* __restrict__ slot2src)
{
    int e = blockIdx.x * 256 + threadIdx.x;
    if (e >= NE) return;
    int s = ei[e], d = ei[NE + e];
    float a[6];
#pragma unroll
    for (int i = 0; i < 6; ++i) a[i] = ea[e * 6 + i];
    int slot_s = rps[s] + atomicAdd(&fs[s], 1);
    int slot_d = rpd[d] + atomicAdd(&fd[d], 1);
    ss2sd[slot_s] = slot_d;
    slot2src[slot_s] = s;
#pragma unroll
    for (int j = 0; j < 16; ++j) {
        float v = k1b[j];
#pragma unroll
        for (int i = 0; i < 6; ++i) v = fmaf(a[i], k1w[i * 16 + j], v);
        eks[(size_t)slot_s * 16 + j] = fmaxf(v, 0.f);
    }
}

// ---------------- GwT hi/lo bf16, [1152 rows n][64 cols k] -----------------
__global__ __launch_bounds__(256) void gwt_kernel(
    const float* __restrict__ k2w, const float* __restrict__ k2b,
    const float* __restrict__ rootw,
    unsigned short* __restrict__ Gh, unsigned short* __restrict__ Gl)
{
    int idx = blockIdx.x * 256 + threadIdx.x;   // 1152*64
    if (idx >= 1152 * 64) return;
    int n = idx >> 6, k = idx & 63;
    int b = n >> 6, o = n & 63;
    float g;
    if (b < 16)       g = k2w[b * 4096 + k * 64 + o];
    else if (b == 16) g = k2b[k * 64 + o];
    else              g = rootw[k * 64 + o];
    unsigned short hi = f2bf(g);
    Gh[idx] = hi;
    Gl[idx] = f2bf(g - bf2f(hi));
}

// ---------------- h0 = x*fc1_w + fc1_b -> hi/lo bf16 ----------------
__global__ __launch_bounds__(256) void h0_kernel(
    const float* __restrict__ x, const float* __restrict__ w,
    const float* __restrict__ b,
    unsigned short* __restrict__ hhi, unsigned short* __restrict__ hlo)
{
    int idx = blockIdx.x * 256 + threadIdx.x;
    if (idx >= NN * WD) return;
    int n = idx >> 6, o = idx & 63;
    float v = fmaf(x[n], w[o], b[o]);
    unsigned short hi = f2bf(v);
    hhi[idx] = hi;
    hlo[idx] = f2bf(v - bf2f(hi));
}

// ---------------- fused: MFMA P->LDS (+Proot->global), then edge combine ----
__global__ __launch_bounds__(512) void fused_kernel(
    const unsigned short* __restrict__ hhi, const unsigned short* __restrict__ hlo,
    const unsigned short* __restrict__ Gh, const unsigned short* __restrict__ Gl,
    const float* __restrict__ eks, const int* __restrict__ ss2sd,
    const int* __restrict__ slot2src, const int* __restrict__ rps,
    float* __restrict__ Proot, float* __restrict__ msg)
{
    __shared__ __align__(16) float Pt[TM * LSTR];   // 65,520 B
    int n0 = blockIdx.x * TM;
    int w = threadIdx.x >> 6, l = threadIdx.x & 63;
    int quad = l >> 4, lr = l & 15;
    int arow = n0 + lr;
    if (arow > NN - 1) arow = NN - 1;
    const bf16x8* pah = (const bf16x8*)(hhi + (size_t)arow * 64 + quad * 8);
    const bf16x8* pal = (const bf16x8*)(hlo + (size_t)arow * 64 + quad * 8);
    bf16x8 ah0 = pah[0], ah1 = pah[4];   // k 0..31, 32..63
    bf16x8 al0 = pal[0], al1 = pal[4];

    for (int st = w; st < 18; st += 8) {
        f32x4 acc[4];
#pragma unroll
        for (int t = 0; t < 4; ++t) acc[t] = (f32x4){0.f, 0.f, 0.f, 0.f};
#pragma unroll
        for (int t = 0; t < 4; ++t) {
            int brow = st * 64 + t * 16 + lr;
            const bf16x8* pbh = (const bf16x8*)(Gh + (size_t)brow * 64 + quad * 8);
            const bf16x8* pbl = (const bf16x8*)(Gl + (size_t)brow * 64 + quad * 8);
            bf16x8 bh0 = pbh[0], bh1 = pbh[4];
            bf16x8 bl0 = pbl[0], bl1 = pbl[4];
            f32x4 a = acc[t];
            a = __builtin_amdgcn_mfma_f32_16x16x32_bf16(ah0, bh0, a, 0, 0, 0);
            a = __builtin_amdgcn_mfma_f32_16x16x32_bf16(ah0, bl0, a, 0, 0, 0);
            a = __builtin_amdgcn_mfma_f32_16x16x32_bf16(al0, bh0, a, 0, 0, 0);
            a = __builtin_amdgcn_mfma_f32_16x16x32_bf16(ah1, bh1, a, 0, 0, 0);
            a = __builtin_amdgcn_mfma_f32_16x16x32_bf16(ah1, bl1, a, 0, 0, 0);
            a = __builtin_amdgcn_mfma_f32_16x16x32_bf16(al1, bh1, a, 0, 0, 0);
            acc[t] = a;
        }
        // C/D layout: col = lane&15, row = quad*4 + reg
        if (st < 17) {
#pragma unroll
            for (int t = 0; t < 4; ++t)
#pragma unroll
                for (int r = 0; r < 4; ++r) {
                    int row = quad * 4 + r;
                    if (row < TM)
                        Pt[row * LSTR + st * 64 + t * 16 + lr] = acc[t][r];
                }
        } else {
#pragma unroll
            for (int t = 0; t < 4; ++t)
#pragma unroll
                for (int r = 0; r < 4; ++r) {
                    int row = quad * 4 + r;
                    int gn = n0 + row;
                    if (row < TM && gn < NN)
                        Proot[(size_t)gn * 64 + t * 16 + lr] = acc[t][r];
                }
        }
    }
    __syncthreads();

    // edge phase: 8 waves stride the tile's contiguous src-slot range
    int nend = n0 + TM; if (nend > NN) nend = NN;
    int r0 = rps[n0], r1 = rps[nend];
    for (int s = r0 + w; s < r1; s += 8) {
        int ln = slot2src[s] - n0;
        float ekv = eks[(size_t)s * 16 + (l & 15)];
        int ds = ss2sd[s];
        const float* Pr = &Pt[ln * LSTR];
        float m = Pr[16 * 64 + l];   // bias strip
#pragma unroll
        for (int k = 0; k < 16; ++k)
            m = fmaf(__shfl(ekv, k, 64), Pr[k * 64 + l], m);
        msg[(size_t)ds * 64 + l] = m;
    }
}

// ---------------- per-dst sum (coalesced) + fused epilogue ----------------
__global__ __launch_bounds__(256) void agg_kernel(
    const float* __restrict__ msg, const int* __restrict__ rpd,
    const float* __restrict__ invd, const float* __restrict__ Proot,
    const float* __restrict__ convb, float* __restrict__ h,
    unsigned short* __restrict__ hhi, unsigned short* __restrict__ hlo)
{
    int i = blockIdx.x * 4 + (threadIdx.x >> 6);
    if (i >= NN) return;
    int l = threadIdx.x & 63;
    int r0 = rpd[i], r1 = rpd[i + 1];
    float acc = 0.f;
    for (int s = r0; s < r1; ++s) acc += msg[(size_t)s * 64 + l];
    float v = fmaf(acc, invd[i], Proot[(size_t)i * 64 + l] + convb[l]);
    v = fmaxf(v, 0.f);
    int idx = i * 64 + l;
    h[idx] = v;
    unsigned short hi = f2bf(v);
    hhi[idx] = hi;
    hlo[idx] = f2bf(v - bf2f(hi));
}

// ---------------- out = h @ fc2_w + fc2_b ----------------
__global__ __launch_bounds__(256) void out_kernel(
    const float* __restrict__ h, const float* __restrict__ fc2_w,
    const float* __restrict__ fc2_b, float* __restrict__ out)
{
    int wave = blockIdx.x * 4 + (threadIdx.x >> 6);
    int lane = threadIdx.x & 63;
    float v = h[(size_t)wave * 64 + lane] * fc2_w[lane];
#pragma unroll
    for (int off = 32; off > 0; off >>= 1) v += __shfl_down(v, off);
    if (lane == 0) out[wave] = v + fc2_b[0];
}

extern "C" void kernel_launch(void* const* d_in, const int* in_sizes, int n_in,
                              void* d_out, int out_size, void* d_ws, size_t ws_size,
                              hipStream_t stream)
{
    const float* x         = (const float*)d_in[0];
    const int*   ei        = (const int*)  d_in[1];
    const float* edge_attr = (const float*)d_in[2];
    const float* fc1_w     = (const float*)d_in[3];
    const float* fc1_b     = (const float*)d_in[4];
    const float* k1_w      = (const float*)d_in[5];
    const float* k1_b      = (const float*)d_in[6];
    const float* k2_w      = (const float*)d_in[7];
    const float* k2_b      = (const float*)d_in[8];
    const float* root_w    = (const float*)d_in[9];
    const float* conv_b    = (const float*)d_in[10];
    const float* fc2_w     = (const float*)d_in[11];
    const float* fc2_b     = (const float*)d_in[12];
    float* out = (float*)d_out;

    // workspace layout, f32 units
    float* ws = (float*)d_ws;
    size_t off = 0;
    int* cnt   = (int*)(ws + off); off += 4 * NN;       // outc|inc|fs|fd
    int* outc  = cnt;
    int* inc   = cnt + NN;
    int* fs    = cnt + 2 * NN;
    int* fd    = cnt + 3 * NN;
    int* rps   = (int*)(ws + off); off += 20004;
    int* rpd   = (int*)(ws + off); off += 20004;
    int* partials = (int*)(ws + off); off += 64;
    int* bases    = (int*)(ws + off); off += 64;
    int* ss2sd    = (int*)(ws + off); off += NE;
    int* slot2src = (int*)(ws + off); off += NE;
    float* invd  = ws + off; off += NN;
    float* eks   = ws + off; off += (size_t)NE * 16;
    unsigned short* Gh  = (unsigned short*)(ws + off); off += 36864;
    unsigned short* Gl  = (unsigned short*)(ws + off); off += 36864;
    unsigned short* hhi = (unsigned short*)(ws + off); off += (size_t)NN * 32;
    unsigned short* hlo = (unsigned short*)(ws + off); off += (size_t)NN * 32;
    float* h     = ws + off; off += (size_t)NN * WD;
    float* msg   = ws + off; off += (size_t)NE * WD;
    float* Proot = ws + off; off += (size_t)NN * WD;

    hipMemsetAsync(cnt, 0, 4 * NN * sizeof(int), stream);
    count_kernel<<<(NE + 255) / 256, 256, 0, stream>>>(ei, outc, inc);
    scanA_kernel<<<40, 256, 0, stream>>>(cnt, partials);
    scanB_kernel<<<1, 64, 0, stream>>>(partials, bases);
    scanC_kernel<<<40, 256, 0, stream>>>(cnt, bases, rps, rpd, invd);
    ekfill_kernel<<<(NE + 255) / 256, 256, 0, stream>>>(ei, edge_attr, k1_w, k1_b,
                                                        rps, rpd, fs, fd, eks,
                                                        ss2sd, slot2src);
    gwt_kernel<<<(1152 * 64 + 255) / 256, 256, 0, stream>>>(k2_w, k2_b, root_w, Gh, Gl);
    h0_kernel<<<(NN * WD + 255) / 256, 256, 0, stream>>>(x, fc1_w, fc1_b, hhi, hlo);

    int ntiles = (NN + TM - 1) / TM;   // 1334
    for (int layer = 0; layer < DEPTH; ++layer) {
        fused_kernel<<<ntiles, 512, 0, stream>>>(hhi, hlo, Gh, Gl, eks, ss2sd,
                                                 slot2src, rps, Proot, msg);
        agg_kernel<<<(NN + 3) / 4, 256, 0, stream>>>(msg, rpd, invd, Proot,
                                                     conv_b, h, hhi, hlo);
    }

    out_kernel<<<NN / 4, 256, 0, stream>>>(h, fc2_w, fc2_b, out);
}

// Round 7
// 561.815 us; speedup vs baseline: 1.6628x; 1.1182x over previous
//
#include <hip/hip_runtime.h>
#include <hip/hip_bf16.h>

// NNConv GNN, round 7:
//  Fused per-layer kernel: 512-thread blocks own a 15-node tile. 8 waves
//  compute P_tile = h_tile @ [K_0..K_15|Bmat] via split-bf16 MFMA into LDS
//  (65,520 B; P never touches HBM) + Proot strip to global. Edge phase:
//  each wave takes a CONTIGUOUS sub-range of the tile's src-CSR slot range;
//  slot index is wave-uniform -> readfirstlane + scalar (SMEM) loads of eks
//  row / ss2sd, 16 FMAs with SGPR operands (NO shfl chain — R6's 77 us was
//  ~1.9k cyc/slot of serial ds_bpermute latency), P row register-cached and
//  reloaded from LDS only on node change. msg scattered to dst-CSR order so
//  the agg pass streams coalesced (4-way ILP unrolled).
//  CSR built per call: count -> hierarchical 3-kernel scan -> fill.

#define NN 20000
#define NE 100000
#define WD 64
#define DEPTH 6
#define TM 15            // nodes per tile (row 15 of the MFMA tile wasted)
#define LSTR 1092        // LDS row stride (words): 1092%32==4 -> 2-way only

typedef __attribute__((ext_vector_type(8))) short bf16x8;
typedef __attribute__((ext_vector_type(4))) float f32x4;

__device__ __forceinline__ unsigned short f2bf(float v) {
    union { float f; unsigned u; } x; x.f = v;
    unsigned r = x.u + 0x7fffu + ((x.u >> 16) & 1u);
    return (unsigned short)(r >> 16);
}
__device__ __forceinline__ float bf2f(unsigned short b) {
    union { unsigned u; float f; } x; x.u = ((unsigned)b) << 16;
    return x.f;
}

// ---------------- per-node in/out degree counts ----------------
__global__ __launch_bounds__(256) void count_kernel(const int* __restrict__ ei,
                                                    int* __restrict__ outc,
                                                    int* __restrict__ inc)
{
    int e = blockIdx.x * 256 + threadIdx.x;
    if (e >= NE) return;
    atomicAdd(&outc[ei[e]], 1);
    atomicAdd(&inc[ei[NE + e]], 1);
}

// ---------------- hierarchical scan over [outc | inc] (40000 ints) ----------
__global__ __launch_bounds__(256) void scanA_kernel(const int* __restrict__ cnt,
                                                    int* __restrict__ partials)
{
    int b = blockIdx.x, t = threadIdx.x, lane = t & 63, w = t >> 6;
    int base = b * 1024 + t * 4;
    int s = 0;
#pragma unroll
    for (int i = 0; i < 4; ++i) {
        int idx = base + i;
        if (idx < 2 * NN) s += cnt[idx];
    }
#pragma unroll
    for (int off = 32; off > 0; off >>= 1) s += __shfl_down(s, off, 64);
    __shared__ int wsum[4];
    if (lane == 0) wsum[w] = s;
    __syncthreads();
    if (t == 0) partials[b] = wsum[0] + wsum[1] + wsum[2] + wsum[3];
}

__global__ __launch_bounds__(64) void scanB_kernel(const int* __restrict__ partials,
                                                   int* __restrict__ bases)
{
    int l = threadIdx.x;
    int p = (l < 40) ? partials[l] : 0;
    int v = p;
#pragma unroll
    for (int off = 1; off < 64; off <<= 1) {
        int u = __shfl_up(v, off, 64);
        if (l >= off) v += u;
    }
    if (l < 40) bases[l] = v - p;   // exclusive
}

__global__ __launch_bounds__(256) void scanC_kernel(const int* __restrict__ cnt,
                                                    const int* __restrict__ bases,
                                                    int* __restrict__ rps,
                                                    int* __restrict__ rpd,
                                                    float* __restrict__ invd)
{
    int b = blockIdx.x, t = threadIdx.x, lane = t & 63, w = t >> 6;
    int base = b * 1024 + t * 4;
    int v[4], s = 0;
#pragma unroll
    for (int i = 0; i < 4; ++i) {
        int idx = base + i;
        v[i] = (idx < 2 * NN) ? cnt[idx] : 0;
        s += v[i];
    }
    int tsum = s, sc = s;
#pragma unroll
    for (int off = 1; off < 64; off <<= 1) {
        int u = __shfl_up(sc, off, 64);
        if (lane >= off) sc += u;
    }
    __shared__ int wtot[4];
    if (lane == 63) wtot[w] = sc;
    __syncthreads();
    int wbase = 0;
    for (int j = 0; j < w; ++j) wbase += wtot[j];
    int run = bases[b] + wbase + sc - tsum;
#pragma unroll
    for (int i = 0; i < 4; ++i) {
        int idx = base + i;
        int e = run; run += v[i];
        if (idx < NN) {
            rps[idx] = e;
        } else if (idx < 2 * NN) {
            rpd[idx - NN] = e - NE;           // first-half total == NE
            invd[idx - NN] = 1.0f / fmaxf((float)v[i], 1.0f);
        }
    }
    if (b == 0 && t == 0) { rps[NN] = NE; rpd[NN] = NE; }
}

// ---------------- ek MLP + CSR fill ----------------
__global__ __launch_bounds__(256) void ekfill_kernel(
    const int* __restrict__ ei, const float* __restrict__ ea,
    const float* __restrict__ k1w, const float* __restrict__ k1b,
    const int* __restrict__ rps, const int* __restrict__ rpd,
    int* __restrict__ fs, int* __restrict__ fd,
    float* __restrict__ eks, int* __restrict__ ss2sd)
{
    int e = blockIdx.x * 256 + threadIdx.x;
    if (e >= NE) return;
    int s = ei[e], d = ei[NE + e];
    float a[6];
#pragma unroll
    for (int i = 0; i < 6; ++i) a[i] = ea[e * 6 + i];
    int slot_s = rps[s] + atomicAdd(&fs[s], 1);
    int slot_d = rpd[d] + atomicAdd(&fd[d], 1);
    ss2sd[slot_s] = slot_d;
#pragma unroll
    for (int j = 0; j < 16; ++j) {
        float v = k1b[j];
#pragma unroll
        for (int i = 0; i < 6; ++i) v = fmaf(a[i], k1w[i * 16 + j], v);
        eks[(size_t)slot_s * 16 + j] = fmaxf(v, 0.f);
    }
}

// ---------------- GwT hi/lo bf16, [1152 rows n][64 cols k] -----------------
__global__ __launch_bounds__(256) void gwt_kernel(
    const float* __restrict__ k2w, const float* __restrict__ k2b,
    const float* __restrict__ rootw,
    unsigned short* __restrict__ Gh, unsigned short* __restrict__ Gl)
{
    int idx = blockIdx.x * 256 + threadIdx.x;   // 1152*64
    if (idx >= 1152 * 64) return;
    int n = idx >> 6, k = idx & 63;
    int b = n >> 6, o = n & 63;
    float g;
    if (b < 16)       g = k2w[b * 4096 + k * 64 + o];
    else if (b == 16) g = k2b[k * 64 + o];
    else              g = rootw[k * 64 + o];
    unsigned short hi = f2bf(g);
    Gh[idx] = hi;
    Gl[idx] = f2bf(g - bf2f(hi));
}

// ---------------- h0 = x*fc1_w + fc1_b -> hi/lo bf16 ----------------
__global__ __launch_bounds__(256) void h0_kernel(
    const float* __restrict__ x, const float* __restrict__ w,
    const float* __restrict__ b,
    unsigned short* __restrict__ hhi, unsigned short* __restrict__ hlo)
{
    int idx = blockIdx.x * 256 + threadIdx.x;
    if (idx >= NN * WD) return;
    int n = idx >> 6, o = idx & 63;
    float v = fmaf(x[n], w[o], b[o]);
    unsigned short hi = f2bf(v);
    hhi[idx] = hi;
    hlo[idx] = f2bf(v - bf2f(hi));
}

// ---------------- fused: MFMA P->LDS (+Proot->global), then edge combine ----
__global__ __launch_bounds__(512) void fused_kernel(
    const unsigned short* __restrict__ hhi, const unsigned short* __restrict__ hlo,
    const unsigned short* __restrict__ Gh, const unsigned short* __restrict__ Gl,
    const float* __restrict__ eks, const int* __restrict__ ss2sd,
    const int* __restrict__ rps, float* __restrict__ Proot,
    float* __restrict__ msg)
{
    __shared__ __align__(16) float Pt[TM * LSTR];   // 65,520 B
    __shared__ int rb[TM + 1];
    int n0 = blockIdx.x * TM;
    int w = threadIdx.x >> 6, l = threadIdx.x & 63;
    int quad = l >> 4, lr = l & 15;
    if (threadIdx.x < TM + 1) {
        int gi = n0 + threadIdx.x;
        rb[threadIdx.x] = rps[gi > NN ? NN : gi];
    }
    int arow = n0 + lr;
    if (arow > NN - 1) arow = NN - 1;
    const bf16x8* pah = (const bf16x8*)(hhi + (size_t)arow * 64 + quad * 8);
    const bf16x8* pal = (const bf16x8*)(hlo + (size_t)arow * 64 + quad * 8);
    bf16x8 ah0 = pah[0], ah1 = pah[4];   // k 0..31, 32..63
    bf16x8 al0 = pal[0], al1 = pal[4];

    for (int st = w; st < 18; st += 8) {
        f32x4 acc[4];
#pragma unroll
        for (int t = 0; t < 4; ++t) acc[t] = (f32x4){0.f, 0.f, 0.f, 0.f};
#pragma unroll
        for (int t = 0; t < 4; ++t) {
            int brow = st * 64 + t * 16 + lr;
            const bf16x8* pbh = (const bf16x8*)(Gh + (size_t)brow * 64 + quad * 8);
            const bf16x8* pbl = (const bf16x8*)(Gl + (size_t)brow * 64 + quad * 8);
            bf16x8 bh0 = pbh[0], bh1 = pbh[4];
            bf16x8 bl0 = pbl[0], bl1 = pbl[4];
            f32x4 a = acc[t];
            a = __builtin_amdgcn_mfma_f32_16x16x32_bf16(ah0, bh0, a, 0, 0, 0);
            a = __builtin_amdgcn_mfma_f32_16x16x32_bf16(ah0, bl0, a, 0, 0, 0);
            a = __builtin_amdgcn_mfma_f32_16x16x32_bf16(al0, bh0, a, 0, 0, 0);
            a = __builtin_amdgcn_mfma_f32_16x16x32_bf16(ah1, bh1, a, 0, 0, 0);
            a = __builtin_amdgcn_mfma_f32_16x16x32_bf16(ah1, bl1, a, 0, 0, 0);
            a = __builtin_amdgcn_mfma_f32_16x16x32_bf16(al1, bh1, a, 0, 0, 0);
            acc[t] = a;
        }
        // C/D layout: col = lane&15, row = quad*4 + reg
        if (st < 17) {
#pragma unroll
            for (int t = 0; t < 4; ++t)
#pragma unroll
                for (int r = 0; r < 4; ++r) {
                    int row = quad * 4 + r;
                    if (row < TM)
                        Pt[row * LSTR + st * 64 + t * 16 + lr] = acc[t][r];
                }
        } else {
#pragma unroll
            for (int t = 0; t < 4; ++t)
#pragma unroll
                for (int r = 0; r < 4; ++r) {
                    int row = quad * 4 + r;
                    int gn = n0 + row;
                    if (row < TM && gn < NN)
                        Proot[(size_t)gn * 64 + t * 16 + lr] = acc[t][r];
                }
        }
    }
    __syncthreads();

    // edge phase: contiguous per-wave slot sub-ranges; slot is wave-uniform.
    int nend = n0 + TM; if (nend > NN) nend = NN;
    int r0 = rb[0], r1 = rb[nend - n0];
    int total = r1 - r0;
    if (total <= 0) return;
    int per = (total + 7) >> 3;
    int s0 = r0 + w * per;
    int s1 = s0 + per; if (s1 > r1) s1 = r1;
    int ln = 0;
    float p[17];
    bool need = true;
    for (int s = s0; s < s1; ++s) {
        while (s >= rb[ln + 1]) { ++ln; need = true; }
        if (need) {
            const float* Pr = &Pt[ln * LSTR];
#pragma unroll
            for (int k = 0; k < 17; ++k) p[k] = Pr[k * 64 + l];
            need = false;
        }
        int su = __builtin_amdgcn_readfirstlane(s);
        const float* er = eks + (size_t)su * 16;
        f32x4 e0 = *(const f32x4*)(er);
        f32x4 e1 = *(const f32x4*)(er + 4);
        f32x4 e2 = *(const f32x4*)(er + 8);
        f32x4 e3 = *(const f32x4*)(er + 12);
        int ds = ss2sd[su];
        float ma = p[16], mb = 0.f;   // two chains for ILP
        ma = fmaf(e0[0], p[0], ma);  mb = fmaf(e0[1], p[1], mb);
        ma = fmaf(e0[2], p[2], ma);  mb = fmaf(e0[3], p[3], mb);
        ma = fmaf(e1[0], p[4], ma);  mb = fmaf(e1[1], p[5], mb);
        ma = fmaf(e1[2], p[6], ma);  mb = fmaf(e1[3], p[7], mb);
        ma = fmaf(e2[0], p[8], ma);  mb = fmaf(e2[1], p[9], mb);
        ma = fmaf(e2[2], p[10], ma); mb = fmaf(e2[3], p[11], mb);
        ma = fmaf(e3[0], p[12], ma); mb = fmaf(e3[1], p[13], mb);
        ma = fmaf(e3[2], p[14], ma); mb = fmaf(e3[3], p[15], mb);
        msg[(size_t)ds * 64 + l] = ma + mb;
    }
}

// ---------------- per-dst sum (coalesced, 4-way ILP) + fused epilogue -------
__global__ __launch_bounds__(256) void agg_kernel(
    const float* __restrict__ msg, const int* __restrict__ rpd,
    const float* __restrict__ invd, const float* __restrict__ Proot,
    const float* __restrict__ convb, float* __restrict__ h,
    unsigned short* __restrict__ hhi, unsigned short* __restrict__ hlo)
{
    int i = blockIdx.x * 4 + (threadIdx.x >> 6);
    if (i >= NN) return;
    int l = threadIdx.x & 63;
    int r0 = rpd[i], r1 = rpd[i + 1];
    float a0 = 0.f, a1 = 0.f, a2 = 0.f, a3 = 0.f;
    int s = r0;
    for (; s + 3 < r1; s += 4) {
        a0 += msg[(size_t)s * 64 + l];
        a1 += msg[(size_t)(s + 1) * 64 + l];
        a2 += msg[(size_t)(s + 2) * 64 + l];
        a3 += msg[(size_t)(s + 3) * 64 + l];
    }
    for (; s < r1; ++s) a0 += msg[(size_t)s * 64 + l];
    float acc = (a0 + a1) + (a2 + a3);
    float v = fmaf(acc, invd[i], Proot[(size_t)i * 64 + l] + convb[l]);
    v = fmaxf(v, 0.f);
    int idx = i * 64 + l;
    h[idx] = v;
    unsigned short hi = f2bf(v);
    hhi[idx] = hi;
    hlo[idx] = f2bf(v - bf2f(hi));
}

// ---------------- out = h @ fc2_w + fc2_b ----------------
__global__ __launch_bounds__(256) void out_kernel(
    const float* __restrict__ h, const float* __restrict__ fc2_w,
    const float* __restrict__ fc2_b, float* __restrict__ out)
{
    int wave = blockIdx.x * 4 + (threadIdx.x >> 6);
    int lane = threadIdx.x & 63;
    float v = h[(size_t)wave * 64 + lane] * fc2_w[lane];
#pragma unroll
    for (int off = 32; off > 0; off >>= 1) v += __shfl_down(v, off);
    if (lane == 0) out[wave] = v + fc2_b[0];
}

extern "C" void kernel_launch(void* const* d_in, const int* in_sizes, int n_in,
                              void* d_out, int out_size, void* d_ws, size_t ws_size,
                              hipStream_t stream)
{
    const float* x         = (const float*)d_in[0];
    const int*   ei        = (const int*)  d_in[1];
    const float* edge_attr = (const float*)d_in[2];
    const float* fc1_w     = (const float*)d_in[3];
    const float* fc1_b     = (const float*)d_in[4];
    const float* k1_w      = (const float*)d_in[5];
    const float* k1_b      = (const float*)d_in[6];
    const float* k2_w      = (const float*)d_in[7];
    const float* k2_b      = (const float*)d_in[8];
    const float* root_w    = (const float*)d_in[9];
    const float* conv_b    = (const float*)d_in[10];
    const float* fc2_w     = (const float*)d_in[11];
    const float* fc2_b     = (const float*)d_in[12];
    float* out = (float*)d_out;

    // workspace layout, f32 units
    float* ws = (float*)d_ws;
    size_t off = 0;
    int* cnt   = (int*)(ws + off); off += 4 * NN;       // outc|inc|fs|fd
    int* outc  = cnt;
    int* inc   = cnt + NN;
    int* fs    = cnt + 2 * NN;
    int* fd    = cnt + 3 * NN;
    int* rps   = (int*)(ws + off); off += 20004;
    int* rpd   = (int*)(ws + off); off += 20004;
    int* partials = (int*)(ws + off); off += 64;
    int* bases    = (int*)(ws + off); off += 64;
    int* ss2sd    = (int*)(ws + off); off += NE;
    float* invd  = ws + off; off += NN;
    float* eks   = ws + off; off += (size_t)NE * 16;
    unsigned short* Gh  = (unsigned short*)(ws + off); off += 36864;
    unsigned short* Gl  = (unsigned short*)(ws + off); off += 36864;
    unsigned short* hhi = (unsigned short*)(ws + off); off += (size_t)NN * 32;
    unsigned short* hlo = (unsigned short*)(ws + off); off += (size_t)NN * 32;
    float* h     = ws + off; off += (size_t)NN * WD;
    float* msg   = ws + off; off += (size_t)NE * WD;
    float* Proot = ws + off; off += (size_t)NN * WD;

    hipMemsetAsync(cnt, 0, 4 * NN * sizeof(int), stream);
    count_kernel<<<(NE + 255) / 256, 256, 0, stream>>>(ei, outc, inc);
    scanA_kernel<<<40, 256, 0, stream>>>(cnt, partials);
    scanB_kernel<<<1, 64, 0, stream>>>(partials, bases);
    scanC_kernel<<<40, 256, 0, stream>>>(cnt, bases, rps, rpd, invd);
    ekfill_kernel<<<(NE + 255) / 256, 256, 0, stream>>>(ei, edge_attr, k1_w, k1_b,
                                                        rps, rpd, fs, fd, eks, ss2sd);
    gwt_kernel<<<(1152 * 64 + 255) / 256, 256, 0, stream>>>(k2_w, k2_b, root_w, Gh, Gl);
    h0_kernel<<<(NN * WD + 255) / 256, 256, 0, stream>>>(x, fc1_w, fc1_b, hhi, hlo);

    int ntiles = (NN + TM - 1) / TM;   // 1334
    for (int layer = 0; layer < DEPTH; ++layer) {
        fused_kernel<<<ntiles, 512, 0, stream>>>(hhi, hlo, Gh, Gl, eks, ss2sd,
                                                 rps, Proot, msg);
        agg_kernel<<<(NN + 3) / 4, 256, 0, stream>>>(msg, rpd, invd, Proot,
                                                     conv_b, h, hhi, hlo);
    }

    out_kernel<<<NN / 4, 256, 0, stream>>>(h, fc2_w, fc2_b, out);
}